// Round 5
// baseline (1537.151 us; speedup 1.0000x reference)
//
#include <hip/hip_runtime.h>
#include <hip/hip_bf16.h>

// Problem: B=2, T=256, IN_DIM=512, OUT_DIM=256, H=8, TEMP=1, BN_EPS=1e-5
// Device dtypes: inputs fp32 (boundary int32), OUTPUT fp32 (reference dtype).
// ROUND 5: identical to round 4 except output written as fp32.
#define B_ 2
#define T_ 256
#define D_ 512
#define O_ 256
#define H_ 8

typedef __attribute__((ext_vector_type(4))) float f32x4;
typedef unsigned short u16;
typedef unsigned int u32;

__device__ __forceinline__ float b2f(u16 u) {
    u32 t = ((u32)u) << 16;
    return __builtin_bit_cast(float, t);
}
__device__ __forceinline__ u16 f2b(float f) {
    u32 u = __builtin_bit_cast(u32, f);
    u32 r = (u + 0x7FFFu + ((u >> 16) & 1u)) >> 16;  // RNE
    return (u16)r;
}

// ---------- K0: XT[b][d][k] = bf16(x[b][k][d]) ----------
__global__ void k0_convert(const float* __restrict__ x, u16* __restrict__ XT) {
    int idx = blockIdx.x;  // 64 blocks: ((b*4 + kt)*8 + dt)
    int dt = idx & 7, kt = (idx >> 3) & 3, b = idx >> 5;
    __shared__ u16 tile[64][65];
    int tid = threadIdx.x;
    for (int c = tid; c < 4096; c += 256) {
        int r = c >> 6, col = c & 63;
        tile[r][col] = f2b(x[(b * 256 + kt * 64 + r) * 512 + dt * 64 + col]);
    }
    __syncthreads();
    for (int c = tid; c < 4096; c += 256) {
        int rr = c >> 6, cc = c & 63;
        XT[(b * 512 + dt * 64 + rr) * 256 + kt * 64 + cc] = tile[cc][rr];
    }
}

// ---------- K1' (dead-simple VALU): logits + tanh + att_weight + mask + softmax ----------
// One block per (b,j); thread t = key node k. Direct translation of reference.
__global__ void k1_simple(const float* __restrict__ xf, const int* __restrict__ bnd,
                          const float* __restrict__ Wap, const float* __restrict__ bap,
                          const float* __restrict__ aw, u16* __restrict__ p_ws)
{
    const int b = blockIdx.x >> 8;
    const int j = blockIdx.x & 255;
    const int t = threadIdx.x;  // k index

    __shared__ __align__(16) float xjL[512];
    __shared__ __align__(16) float WL[16][512];
    __shared__ float awL[256 * 8];
    __shared__ float attL[256][8];

    for (int i = t; i < 512; i += 256) xjL[i] = xf[(b * 256 + j) * 512 + i];
    for (int i = t; i < 2048; i += 256) awL[i] = aw[i];

    // mask[j,t] = prod_{m=min..max inclusive} (1 - bnd[m]); diag forced to 1
    float prod = 1.f;
    {
        int lo = j < t ? j : t, hi = j < t ? t : j;
        for (int m = lo; m <= hi; ++m) prod *= (1.f - (float)bnd[b * 256 + m]);
        if (t == j) prod = 1.f;
    }
    __syncthreads();

    float atth[8] = {};
    const float* xrow = xf + (b * 256 + t) * 512;
    for (int oc = 0; oc < 16; ++oc) {      // 16 chunks x 16 output channels
        __syncthreads();
        for (int i = t; i < 16 * 512; i += 256)
            WL[i >> 9][i & 511] = Wap[(oc * 16 + (i >> 9)) * 512 + (i & 511)];
        __syncthreads();
        float s[16] = {};
        for (int d4 = 0; d4 < 128; ++d4) {
            f32x4 xv = *reinterpret_cast<const f32x4*>(xrow + d4 * 4);
            f32x4 xj4 = *reinterpret_cast<const f32x4*>(&xjL[d4 * 4]);
            xv = xv * xj4;   // pm[j,k,d] for 4 d's
            #pragma unroll
            for (int r = 0; r < 16; ++r) {
                f32x4 wv = *reinterpret_cast<const f32x4*>(&WL[r][d4 * 4]);
                s[r] += xv[0] * wv[0] + xv[1] * wv[1] + xv[2] * wv[2] + xv[3] * wv[3];
            }
        }
        #pragma unroll
        for (int r = 0; r < 16; ++r) {
            int o = oc * 16 + r;
            float a = tanhf(s[r] + bap[o]);
            #pragma unroll
            for (int h = 0; h < 8; ++h) atth[h] += a * awL[o * 8 + h];
        }
    }
    #pragma unroll
    for (int h = 0; h < 8; ++h) attL[t][h] = atth[h] * prod;  // mask BEFORE softmax
    __syncthreads();

    // serial softmax over k per head (threads 0..7)
    if (t < 8) {
        int h = t;
        float mx = -3.4e38f;
        for (int k = 0; k < 256; ++k) mx = fmaxf(mx, attL[k][h]);
        float sum = 0.f;
        for (int k = 0; k < 256; ++k) sum += expf(attL[k][h] - mx);
        float inv = 1.f / sum;
        u16* dst = p_ws + ((b * 8 + h) * 256 + j) * 256;
        for (int k = 0; k < 256; ++k) dst[k] = f2b(expf(attL[k][h] - mx) * inv);
    }
}

// ---------- K2' (simple VALU): x1[b][j][d*8+h] = sum_k p[b,h,j,k] * x[b,k,d] ----------
__global__ void k2_simple(const u16* __restrict__ p_ws, const u16* __restrict__ XT,
                          u16* __restrict__ x1)
{
    const int b = blockIdx.x >> 8;
    const int j = blockIdx.x & 255;
    const int tid = threadIdx.x;
    __shared__ float pL[8][256];
    for (int i = tid; i < 2048; i += 256) {
        int h = i >> 8, k = i & 255;
        pL[h][k] = b2f(p_ws[(((b * 8 + h) * 256 + j) * 256) + k]);
    }
    __syncthreads();
    for (int dd = tid; dd < 512; dd += 256) {
        float s[8] = {0.f, 0.f, 0.f, 0.f, 0.f, 0.f, 0.f, 0.f};
        const u16* xr = XT + (b * 512 + dd) * 256;
        for (int k = 0; k < 256; ++k) {
            float xv = b2f(xr[k]);
            #pragma unroll
            for (int h = 0; h < 8; ++h) s[h] += pL[h][k] * xv;
        }
        u16* dst = x1 + (b * 256 + j) * 4096 + dd * 8;
        #pragma unroll
        for (int h = 0; h < 8; ++h) dst[h] = f2b(s[h]);
    }
}

// ---------- K3' (simple VALU): ypre = x1 @ W2^T + x @ W3^T + b2 + b3 ----------
__global__ void k3_simple(const u16* __restrict__ x1, const float* __restrict__ x,
                          const float* __restrict__ W2, const float* __restrict__ W3,
                          const float* __restrict__ pb2, const float* __restrict__ pb3,
                          float* __restrict__ ypre)
{
    const int r0 = blockIdx.x * 4;  // 128 blocks x 4 rows
    const int o = threadIdx.x;      // 256 threads = one output channel each
    __shared__ u16 x1L[4][4096];    // 32 KB
    __shared__ float xL[4][512];    // 8 KB
    for (int i = o; i < 4 * 4096; i += 256)
        x1L[i >> 12][i & 4095] = x1[(r0 + (i >> 12)) * 4096 + (i & 4095)];
    for (int i = o; i < 4 * 512; i += 256)
        xL[i >> 9][i & 511] = x[(r0 + (i >> 9)) * 512 + (i & 511)];
    __syncthreads();
    float acc[4] = {0.f, 0.f, 0.f, 0.f};
    const float* w2r = W2 + o * 4096;
    for (int c = 0; c < 4096; ++c) {
        float wv = w2r[c];
        #pragma unroll
        for (int rr = 0; rr < 4; ++rr) acc[rr] += b2f(x1L[rr][c]) * wv;
    }
    const float* w3r = W3 + o * 512;
    for (int d = 0; d < 512; ++d) {
        float wv = w3r[d];
        #pragma unroll
        for (int rr = 0; rr < 4; ++rr) acc[rr] += xL[rr][d] * wv;
    }
    float bsum = pb2[o] + pb3[o];
    #pragma unroll
    for (int rr = 0; rr < 4; ++rr)
        ypre[(r0 + rr) * 256 + o] = acc[rr] + bsum;
}

// ---------- K4a' (single block): per-channel mean / inv-std ----------
__global__ void k4a_stats(const float* __restrict__ ypre,
                          float* __restrict__ mu, float* __restrict__ inv) {
    int o = threadIdx.x;  // 1 block x 256 threads
    float s = 0.f, q = 0.f;
    for (int r = 0; r < 512; ++r) {
        float v = ypre[r * 256 + o];
        s += v; q += v * v;
    }
    float m = s * (1.f / 512.f);
    float var = q * (1.f / 512.f) - m * m;
    mu[o] = m;
    inv[o] = rsqrtf(var + 1e-5f);
}

// ---------- K4b': normalize + affine + SELU -> FP32 output ----------
__global__ void k4b_norm(const float* __restrict__ ypre,
                         const float* __restrict__ mu, const float* __restrict__ inv,
                         const float* __restrict__ gamma, const float* __restrict__ beta,
                         float* __restrict__ out) {
    int r = blockIdx.x, o = threadIdx.x;  // 512 blocks x 256 threads
    float v = (ypre[r * 256 + o] - mu[o]) * inv[o] * gamma[o] + beta[o];
    const float SC = 1.0507009873554805f, AL = 1.6732632423543772f;
    float ov = v > 0.f ? SC * v : SC * AL * (__expf(v) - 1.f);
    out[r * 256 + o] = ov;
}

extern "C" void kernel_launch(void* const* d_in, const int* in_sizes, int n_in,
                              void* d_out, int out_size, void* d_ws, size_t ws_size,
                              hipStream_t stream) {
    const float* x    = (const float*)d_in[0];
    const int* bnd    = (const int*)d_in[1];
    const float* Wap  = (const float*)d_in[2];
    const float* bap  = (const float*)d_in[3];
    const float* aw   = (const float*)d_in[4];
    const float* W2   = (const float*)d_in[5];
    const float* pb2  = (const float*)d_in[6];
    const float* W3   = (const float*)d_in[7];
    const float* pb3  = (const float*)d_in[8];
    const float* gamma = (const float*)d_in[9];
    const float* beta  = (const float*)d_in[10];
    float* out = (float*)d_out;
    (void)in_sizes; (void)n_in; (void)out_size; (void)ws_size;

    char* ws = (char*)d_ws;
    u16* XT    = (u16*)ws;  ws += (size_t)B_ * D_ * T_ * 2;        // 512 KB
    u16* p_ws  = (u16*)ws;  ws += (size_t)B_ * H_ * T_ * T_ * 2;   // 2 MB
    u16* x1    = (u16*)ws;  ws += (size_t)B_ * T_ * D_ * H_ * 2;   // 4 MB
    float* ypre = (float*)ws; ws += (size_t)B_ * T_ * O_ * 4;      // 512 KB
    float* muv  = (float*)ws; ws += (size_t)O_ * 4;
    float* invv = (float*)ws; ws += (size_t)O_ * 4;

    k0_convert<<<64, 256, 0, stream>>>(x, XT);
    k1_simple<<<512, 256, 0, stream>>>(x, bnd, Wap, bap, aw, p_ws);
    k2_simple<<<512, 256, 0, stream>>>(p_ws, XT, x1);
    k3_simple<<<128, 256, 0, stream>>>(x1, x, W2, W3, pb2, pb3, ypre);
    k4a_stats<<<1, 256, 0, stream>>>(ypre, muv, invv);
    k4b_norm<<<512, 256, 0, stream>>>(ypre, muv, invv, gamma, beta, out);
}

// Round 6
// 221.405 us; speedup vs baseline: 6.9427x; 6.9427x over previous
//
#include <hip/hip_runtime.h>
#include <hip/hip_bf16.h>

// Problem: B=2, T=256, IN_DIM=512, OUT_DIM=256, H=8, TEMP=1, BN_EPS=1e-5
// Device dtypes: inputs fp32 (boundary int32), OUTPUT fp32.
// ROUND 6: restore full MFMA pipeline (verified equivalent in rounds 2-4) + fp32 out.
#define B_ 2
#define T_ 256
#define D_ 512
#define O_ 256
#define H_ 8

typedef __attribute__((ext_vector_type(4))) float f32x4;
typedef __attribute__((ext_vector_type(8))) short bf16x8;
typedef unsigned short u16;
typedef unsigned int u32;

__device__ __forceinline__ float b2f(u16 u) {
    u32 t = ((u32)u) << 16;
    return __builtin_bit_cast(float, t);
}
__device__ __forceinline__ u16 f2b(float f) {
    u32 u = __builtin_bit_cast(u32, f);
    u32 r = (u + 0x7FFFu + ((u >> 16) & 1u)) >> 16;  // RNE
    return (u16)r;
}
__device__ __forceinline__ float fast_tanh(float x) {
    float ax = fabsf(x);
    float e = __expf(-2.f * ax);
    float r = (1.f - e) / (1.f + e);
    return x < 0.f ? -r : r;
}
// load 8 consecutive fp32, convert to 8 bf16 packed in uint4
__device__ __forceinline__ uint4 ld8f2b(const float* __restrict__ p) {
    f32x4 a = *reinterpret_cast<const f32x4*>(p);
    f32x4 b = *reinterpret_cast<const f32x4*>(p + 4);
    u16 t[8] = {f2b(a[0]), f2b(a[1]), f2b(a[2]), f2b(a[3]),
                f2b(b[0]), f2b(b[1]), f2b(b[2]), f2b(b[3])};
    return *reinterpret_cast<uint4*>(t);
}

// ---------- K0: Xbf[b][k][d] = bf16(x), XT[b][d][k] = bf16(x[b][k][d]) ----------
__global__ void k0_convert(const float* __restrict__ x,
                           u16* __restrict__ Xbf, u16* __restrict__ XT) {
    int idx = blockIdx.x;  // 64 blocks: ((b*4 + kt)*8 + dt)
    int dt = idx & 7, kt = (idx >> 3) & 3, b = idx >> 5;
    __shared__ u16 tile[64][65];
    int tid = threadIdx.x;
    for (int c = tid; c < 4096; c += 256) {
        int r = c >> 6, col = c & 63;
        float v = x[(b * 256 + kt * 64 + r) * 512 + dt * 64 + col];
        u16 hv = f2b(v);
        tile[r][col] = hv;
        Xbf[(b * 256 + kt * 64 + r) * 512 + dt * 64 + col] = hv;
    }
    __syncthreads();
    for (int c = tid; c < 4096; c += 256) {
        int rr = c >> 6, cc = c & 63;
        XT[(b * 512 + dt * 64 + rr) * 256 + kt * 64 + cc] = tile[cc][rr];
    }
}

// ---------- K1: fused pair-GEMM + tanh + att_weight + mask + softmax (MFMA) ----------
// One block per (b,j). Output: p_ws[b][h][j][k] (post-softmax weights, bf16).
// Verified bit-equivalent to the simple VALU version (rounds 3/4 identical outputs).
__launch_bounds__(256, 2)
__global__ void k1_att(const u16* __restrict__ Xbf, const float* __restrict__ xf,
                       const int* __restrict__ bnd,
                       const float* __restrict__ Wap, const float* __restrict__ bap,
                       const float* __restrict__ aw, u16* __restrict__ p_ws)
{
    const int b = blockIdx.x >> 8;
    const int j = blockIdx.x & 255;
    const int tid = threadIdx.x;
    const int w = tid >> 6;
    const int l = tid & 63;
    const int l15 = l & 15;
    const int lgp = l >> 4;

    __shared__ __align__(16) u16 XL[256 * 72];   // X tile (k x 64d), pad 72; reused as a_lds
    __shared__ __align__(16) u16 WL[64 * 72];    // (W o-chunk x 64d) * xj
    __shared__ __align__(16) u16 awT[16 * 264];  // att_weight^T [h][o], rows 8..15 zero
    __shared__ float xj[512];
    __shared__ float attraw[256 * 9];            // [k][h] pad 9
    __shared__ float maskv[256];
    __shared__ float biasf[256];
    __shared__ int scanv[256];

    const u16* xb = Xbf + b * (T_ * D_);
    const float* xjp = xf + (b * T_ + j) * D_;
    for (int i = tid; i < D_; i += 256) xj[i] = xjp[i];
    for (int i = tid; i < O_; i += 256) biasf[i] = bap[i];
    for (int i = tid; i < 16 * 264; i += 256) awT[i] = 0;
    scanv[tid] = bnd[b * T_ + tid];
    __syncthreads();
    for (int i = tid; i < O_ * H_; i += 256) {
        int o = i >> 3, h = i & 7;
        awT[h * 264 + o] = f2b(aw[i]);
    }
    // inclusive prefix sum of boundary (Hillis-Steele)
    for (int off = 1; off < 256; off <<= 1) {
        int v = (tid >= off) ? scanv[tid - off] : 0;
        __syncthreads();
        scanv[tid] += v;
        __syncthreads();
    }
    {   // mask[k] = 1 iff no boundary in inclusive range [min(j,k), max(j,k)]; diag=1
        int k = tid;
        float m;
        if (k == j) m = 1.f;
        else if (k > j) m = ((scanv[k] - (j ? scanv[j - 1] : 0)) == 0) ? 1.f : 0.f;
        else m = ((scanv[j] - (k ? scanv[k - 1] : 0)) == 0) ? 1.f : 0.f;
        maskv[k] = m;
    }

    f32x4 attacc[4] = {};  // att[k][h] accumulator frags, per kt

    for (int oc = 0; oc < 4; ++oc) {       // o-chunks of 64
        f32x4 acc[4][4] = {};              // C[k,o] tiles [kt][ot]
        for (int d0 = 0; d0 < D_; d0 += 64) {
            __syncthreads();
            // stage X tile (bf16): rows k=0..255, cols d0..d0+63
            #pragma unroll
            for (int c = 0; c < 8; ++c) {
                int cc = tid + c * 256;
                int r = cc >> 3, s = cc & 7;
                *reinterpret_cast<uint4*>(&XL[r * 72 + s * 8]) =
                    *reinterpret_cast<const uint4*>(xb + r * D_ + d0 + s * 8);
            }
            // stage W tile scaled by xj (fp32 math, single rounding)
            #pragma unroll
            for (int c = 0; c < 2; ++c) {
                int cc = tid + c * 256;
                int r = cc >> 3, s = cc & 7;
                const float* wp = Wap + (oc * 64 + r) * 512 + d0 + s * 8;
                f32x4 va = *reinterpret_cast<const f32x4*>(wp);
                f32x4 vb = *reinterpret_cast<const f32x4*>(wp + 4);
                const float* xq = &xj[d0 + s * 8];
                u16 tmp[8];
                #pragma unroll
                for (int e = 0; e < 4; ++e) tmp[e] = f2b(va[e] * xq[e]);
                #pragma unroll
                for (int e = 0; e < 4; ++e) tmp[4 + e] = f2b(vb[e] * xq[4 + e]);
                *reinterpret_cast<uint4*>(&WL[r * 72 + s * 8]) =
                    *reinterpret_cast<const uint4*>(tmp);
            }
            __syncthreads();
            // C[k,o] += X · Wj^T
            #pragma unroll
            for (int ds = 0; ds < 2; ++ds) {
                bf16x8 bfr[4];
                #pragma unroll
                for (int ot = 0; ot < 4; ++ot)
                    bfr[ot] = *reinterpret_cast<const bf16x8*>(&WL[(ot * 16 + l15) * 72 + ds * 32 + lgp * 8]);
                #pragma unroll
                for (int kt = 0; kt < 4; ++kt) {
                    bf16x8 afr = *reinterpret_cast<const bf16x8*>(&XL[(w * 64 + kt * 16 + l15) * 72 + ds * 32 + lgp * 8]);
                    #pragma unroll
                    for (int ot = 0; ot < 4; ++ot)
                        acc[kt][ot] = __builtin_amdgcn_mfma_f32_16x16x32_bf16(afr, bfr[ot], acc[kt][ot], 0, 0, 0);
                }
            }
        }
        // tanh(s + bias) -> a_lds (aliases XL; each wave touches only its own k-strip)
        u16* a_lds = XL;
        #pragma unroll
        for (int kt = 0; kt < 4; ++kt)
            #pragma unroll
            for (int ot = 0; ot < 4; ++ot)
                #pragma unroll
                for (int i = 0; i < 4; ++i) {
                    int k = w * 64 + kt * 16 + lgp * 4 + i;
                    int ol = ot * 16 + l15;
                    float s = acc[kt][ot][i] + biasf[oc * 64 + ol];
                    a_lds[k * 72 + ol] = f2b(fast_tanh(s));
                }
        // att[k,h] += a[k, o-chunk] · awT[h, o-chunk]^T
        #pragma unroll
        for (int ds = 0; ds < 2; ++ds) {
            bf16x8 bw = *reinterpret_cast<const bf16x8*>(&awT[l15 * 264 + oc * 64 + ds * 32 + lgp * 8]);
            #pragma unroll
            for (int kt = 0; kt < 4; ++kt) {
                bf16x8 af = *reinterpret_cast<const bf16x8*>(&a_lds[(w * 64 + kt * 16 + l15) * 72 + ds * 32 + lgp * 8]);
                attacc[kt] = __builtin_amdgcn_mfma_f32_16x16x32_bf16(af, bw, attacc[kt], 0, 0, 0);
            }
        }
    }

    // spill att logits to LDS
    #pragma unroll
    for (int kt = 0; kt < 4; ++kt) {
        if (l15 < 8) {
            #pragma unroll
            for (int i = 0; i < 4; ++i) {
                int k = w * 64 + kt * 16 + lgp * 4 + i;
                attraw[k * 9 + l15] = attacc[kt][i];
            }
        }
    }
    __syncthreads();

    // mask (multiplicative, pre-softmax!) + softmax over k, per h
    {
        int h = tid >> 5, c = tid & 31;
        float lgv[8];
        float mx = -3.4e38f;
        #pragma unroll
        for (int kk = 0; kk < 8; ++kk) {
            int k = c + kk * 32;
            float v = attraw[k * 9 + h] * maskv[k];
            lgv[kk] = v;
            mx = fmaxf(mx, v);
        }
        #pragma unroll
        for (int off = 1; off < 32; off <<= 1)
            mx = fmaxf(mx, __shfl_xor(mx, off, 32));
        float sum = 0.f;
        #pragma unroll
        for (int kk = 0; kk < 8; ++kk) {
            lgv[kk] = __expf(lgv[kk] - mx);
            sum += lgv[kk];
        }
        #pragma unroll
        for (int off = 1; off < 32; off <<= 1)
            sum += __shfl_xor(sum, off, 32);
        float inv = 1.f / sum;
        u16* dst = p_ws + (((b * 8 + h) * 256 + j) * 256);
        #pragma unroll
        for (int kk = 0; kk < 8; ++kk)
            dst[c + kk * 32] = f2b(lgv[kk] * inv);
    }
}

// ---------- K2: x1[b][j][d*8+h] = sum_k p[b,h,j,k] * x[b,k,d] (MFMA) ----------
__launch_bounds__(256, 2)
__global__ void k2_agg(const u16* __restrict__ p_ws, const u16* __restrict__ XT,
                       u16* __restrict__ x1)
{
    const int bh = blockIdx.x >> 3;  // b*8+h
    const int dc = blockIdx.x & 7;   // 64-wide d chunk
    const int b = bh >> 3;
    const int h = bh & 7;
    const int tid = threadIdx.x;
    const int w = tid >> 6, l = tid & 63, l15 = l & 15, lgp = l >> 4;

    __shared__ __align__(16) u16 AL[256 * 72];
    __shared__ __align__(16) u16 BL[64 * 72];

    const u16* A = p_ws + bh * (256 * 256);          // [j][k]
    const u16* Bx = XT + (b * 512 + dc * 64) * 256;  // [d_local][k]

    f32x4 acc[4][4] = {};
    for (int k0 = 0; k0 < 256; k0 += 64) {
        __syncthreads();
        #pragma unroll
        for (int c = 0; c < 8; ++c) {
            int cc = tid + c * 256;
            int r = cc >> 3, s = cc & 7;
            *reinterpret_cast<uint4*>(&AL[r * 72 + s * 8]) =
                *reinterpret_cast<const uint4*>(A + r * 256 + k0 + s * 8);
        }
        #pragma unroll
        for (int c = 0; c < 2; ++c) {
            int cc = tid + c * 256;
            int r = cc >> 3, s = cc & 7;
            *reinterpret_cast<uint4*>(&BL[r * 72 + s * 8]) =
                *reinterpret_cast<const uint4*>(Bx + r * 256 + k0 + s * 8);
        }
        __syncthreads();
        #pragma unroll
        for (int ds = 0; ds < 2; ++ds) {
            bf16x8 bfr[4];
            #pragma unroll
            for (int ot = 0; ot < 4; ++ot)
                bfr[ot] = *reinterpret_cast<const bf16x8*>(&BL[(ot * 16 + l15) * 72 + ds * 32 + lgp * 8]);
            #pragma unroll
            for (int kt = 0; kt < 4; ++kt) {
                bf16x8 afr = *reinterpret_cast<const bf16x8*>(&AL[(w * 64 + kt * 16 + l15) * 72 + ds * 32 + lgp * 8]);
                #pragma unroll
                for (int ot = 0; ot < 4; ++ot)
                    acc[kt][ot] = __builtin_amdgcn_mfma_f32_16x16x32_bf16(afr, bfr[ot], acc[kt][ot], 0, 0, 0);
            }
        }
    }
    #pragma unroll
    for (int kt = 0; kt < 4; ++kt)
        #pragma unroll
        for (int ot = 0; ot < 4; ++ot)
            #pragma unroll
            for (int i = 0; i < 4; ++i) {
                int jj = w * 64 + kt * 16 + lgp * 4 + i;
                int d = dc * 64 + ot * 16 + l15;
                x1[(b * 256 + jj) * 4096 + d * 8 + h] = f2b(acc[kt][ot][i]);
            }
}

// ---------- K3: ypre = x1 @ W2^T + x @ W3^T + b2 + b3 (MFMA) ----------
__launch_bounds__(256, 2)
__global__ void k3_proj(const u16* __restrict__ x1, const float* __restrict__ x,
                        const float* __restrict__ W2, const float* __restrict__ W3,
                        const float* __restrict__ pb2, const float* __restrict__ pb3,
                        float* __restrict__ ypre)
{
    const int oc = blockIdx.x & 3;
    const int jc = (blockIdx.x >> 2) & 3;
    const int b = blockIdx.x >> 4;
    const int j0 = jc * 64, o0 = oc * 64;
    const int tid = threadIdx.x;
    const int w = tid >> 6, l = tid & 63, l15 = l & 15, lgp = l >> 4;

    __shared__ __align__(16) u16 AL[64 * 72];
    __shared__ __align__(16) u16 BL[64 * 72];

    f32x4 acc[4] = {};
    // phase 1: K = 4096 over (d,h); A = x1 (bf16), B = W2 (fp32 -> bf16 inline)
    for (int t0 = 0; t0 < 4096; t0 += 64) {
        __syncthreads();
        #pragma unroll
        for (int c = 0; c < 2; ++c) {
            int cc = tid + c * 256;
            int r = cc >> 3, s = cc & 7;
            *reinterpret_cast<uint4*>(&AL[r * 72 + s * 8]) =
                *reinterpret_cast<const uint4*>(x1 + (b * 256 + j0 + r) * 4096 + t0 + s * 8);
            *reinterpret_cast<uint4*>(&BL[r * 72 + s * 8]) =
                ld8f2b(W2 + (o0 + r) * 4096 + t0 + s * 8);
        }
        __syncthreads();
        #pragma unroll
        for (int ds = 0; ds < 2; ++ds) {
            bf16x8 afr = *reinterpret_cast<const bf16x8*>(&AL[(w * 16 + l15) * 72 + ds * 32 + lgp * 8]);
            #pragma unroll
            for (int ot = 0; ot < 4; ++ot) {
                bf16x8 bfr = *reinterpret_cast<const bf16x8*>(&BL[(ot * 16 + l15) * 72 + ds * 32 + lgp * 8]);
                acc[ot] = __builtin_amdgcn_mfma_f32_16x16x32_bf16(afr, bfr, acc[ot], 0, 0, 0);
            }
        }
    }
    // phase 2: K = 512 over d; A = x (fp32 -> bf16), B = W3 (fp32 -> bf16)
    for (int t0 = 0; t0 < 512; t0 += 64) {
        __syncthreads();
        #pragma unroll
        for (int c = 0; c < 2; ++c) {
            int cc = tid + c * 256;
            int r = cc >> 3, s = cc & 7;
            *reinterpret_cast<uint4*>(&AL[r * 72 + s * 8]) =
                ld8f2b(x + (b * 256 + j0 + r) * 512 + t0 + s * 8);
            *reinterpret_cast<uint4*>(&BL[r * 72 + s * 8]) =
                ld8f2b(W3 + (o0 + r) * 512 + t0 + s * 8);
        }
        __syncthreads();
        #pragma unroll
        for (int ds = 0; ds < 2; ++ds) {
            bf16x8 afr = *reinterpret_cast<const bf16x8*>(&AL[(w * 16 + l15) * 72 + ds * 32 + lgp * 8]);
            #pragma unroll
            for (int ot = 0; ot < 4; ++ot) {
                bf16x8 bfr = *reinterpret_cast<const bf16x8*>(&BL[(ot * 16 + l15) * 72 + ds * 32 + lgp * 8]);
                acc[ot] = __builtin_amdgcn_mfma_f32_16x16x32_bf16(afr, bfr, acc[ot], 0, 0, 0);
            }
        }
    }
    #pragma unroll
    for (int ot = 0; ot < 4; ++ot)
        #pragma unroll
        for (int i = 0; i < 4; ++i) {
            int jj = j0 + w * 16 + lgp * 4 + i;
            int o = o0 + ot * 16 + l15;
            float v = acc[ot][i] + pb2[o] + pb3[o];
            ypre[(b * 256 + jj) * 256 + o] = v;
        }
}

// ---------- K4a (single block): per-channel mean / inv-std ----------
__global__ void k4a_stats(const float* __restrict__ ypre,
                          float* __restrict__ mu, float* __restrict__ inv) {
    int o = threadIdx.x;  // 1 block x 256 threads
    float s = 0.f, q = 0.f;
    for (int r = 0; r < 512; ++r) {
        float v = ypre[r * 256 + o];
        s += v; q += v * v;
    }
    float m = s * (1.f / 512.f);
    float var = q * (1.f / 512.f) - m * m;
    mu[o] = m;
    inv[o] = rsqrtf(var + 1e-5f);
}

// ---------- K4b: normalize + affine + SELU -> FP32 output ----------
__global__ void k4b_norm(const float* __restrict__ ypre,
                         const float* __restrict__ mu, const float* __restrict__ inv,
                         const float* __restrict__ gamma, const float* __restrict__ beta,
                         float* __restrict__ out) {
    int r = blockIdx.x, o = threadIdx.x;  // 512 blocks x 256 threads
    float v = (ypre[r * 256 + o] - mu[o]) * inv[o] * gamma[o] + beta[o];
    const float SC = 1.0507009873554805f, AL = 1.6732632423543772f;
    float ov = v > 0.f ? SC * v : SC * AL * (__expf(v) - 1.f);
    out[r * 256 + o] = ov;
}

extern "C" void kernel_launch(void* const* d_in, const int* in_sizes, int n_in,
                              void* d_out, int out_size, void* d_ws, size_t ws_size,
                              hipStream_t stream) {
    const float* x    = (const float*)d_in[0];
    const int* bnd    = (const int*)d_in[1];
    const float* Wap  = (const float*)d_in[2];
    const float* bap  = (const float*)d_in[3];
    const float* aw   = (const float*)d_in[4];
    const float* W2   = (const float*)d_in[5];
    const float* pb2  = (const float*)d_in[6];
    const float* W3   = (const float*)d_in[7];
    const float* pb3  = (const float*)d_in[8];
    const float* gamma = (const float*)d_in[9];
    const float* beta  = (const float*)d_in[10];
    float* out = (float*)d_out;
    (void)in_sizes; (void)n_in; (void)out_size; (void)ws_size;

    char* ws = (char*)d_ws;
    u16* Xbf   = (u16*)ws;  ws += (size_t)B_ * T_ * D_ * 2;        // 512 KB
    u16* XT    = (u16*)ws;  ws += (size_t)B_ * D_ * T_ * 2;        // 512 KB
    u16* p_ws  = (u16*)ws;  ws += (size_t)B_ * H_ * T_ * T_ * 2;   // 2 MB
    u16* x1    = (u16*)ws;  ws += (size_t)B_ * T_ * D_ * H_ * 2;   // 4 MB
    float* ypre = (float*)ws; ws += (size_t)B_ * T_ * O_ * 4;      // 512 KB
    float* muv  = (float*)ws; ws += (size_t)O_ * 4;
    float* invv = (float*)ws; ws += (size_t)O_ * 4;

    k0_convert<<<64, 256, 0, stream>>>(x, Xbf, XT);
    k1_att<<<512, 256, 0, stream>>>(Xbf, x, bnd, Wap, bap, aw, p_ws);
    k2_agg<<<128, 256, 0, stream>>>(p_ws, XT, x1);
    k3_proj<<<32, 256, 0, stream>>>(x1, x, W2, W3, pb2, pb3, ypre);
    k4a_stats<<<1, 256, 0, stream>>>(ypre, muv, invv);
    k4b_norm<<<512, 256, 0, stream>>>(ypre, muv, invv, gamma, beta, out);
}

// Round 7
// 121.553 us; speedup vs baseline: 12.6459x; 1.8215x over previous
//
#include <hip/hip_runtime.h>
#include <hip/hip_bf16.h>

// Problem: B=2, T=256, IN_DIM=512, OUT_DIM=256, H=8, TEMP=1, BN_EPS=1e-5
// Device dtypes: inputs fp32 (boundary int32), OUTPUT fp32.
// ROUND 7: k3 split-K parallelization (32 -> 160 blocks) + fused combine/stats.
#define B_ 2
#define T_ 256
#define D_ 512
#define O_ 256
#define H_ 8

typedef __attribute__((ext_vector_type(4))) float f32x4;
typedef __attribute__((ext_vector_type(8))) short bf16x8;
typedef unsigned short u16;
typedef unsigned int u32;

__device__ __forceinline__ float b2f(u16 u) {
    u32 t = ((u32)u) << 16;
    return __builtin_bit_cast(float, t);
}
__device__ __forceinline__ u16 f2b(float f) {
    u32 u = __builtin_bit_cast(u32, f);
    u32 r = (u + 0x7FFFu + ((u >> 16) & 1u)) >> 16;  // RNE
    return (u16)r;
}
__device__ __forceinline__ float fast_tanh(float x) {
    float ax = fabsf(x);
    float e = __expf(-2.f * ax);
    float r = (1.f - e) / (1.f + e);
    return x < 0.f ? -r : r;
}
// load 8 consecutive fp32, convert to 8 bf16 packed in uint4
__device__ __forceinline__ uint4 ld8f2b(const float* __restrict__ p) {
    f32x4 a = *reinterpret_cast<const f32x4*>(p);
    f32x4 b = *reinterpret_cast<const f32x4*>(p + 4);
    u16 t[8] = {f2b(a[0]), f2b(a[1]), f2b(a[2]), f2b(a[3]),
                f2b(b[0]), f2b(b[1]), f2b(b[2]), f2b(b[3])};
    return *reinterpret_cast<uint4*>(t);
}

// ---------- K0: Xbf[b][k][d] = bf16(x), XT[b][d][k] = bf16(x[b][k][d]) ----------
__global__ void k0_convert(const float* __restrict__ x,
                           u16* __restrict__ Xbf, u16* __restrict__ XT) {
    int idx = blockIdx.x;  // 64 blocks: ((b*4 + kt)*8 + dt)
    int dt = idx & 7, kt = (idx >> 3) & 3, b = idx >> 5;
    __shared__ u16 tile[64][65];
    int tid = threadIdx.x;
    for (int c = tid; c < 4096; c += 256) {
        int r = c >> 6, col = c & 63;
        float v = x[(b * 256 + kt * 64 + r) * 512 + dt * 64 + col];
        u16 hv = f2b(v);
        tile[r][col] = hv;
        Xbf[(b * 256 + kt * 64 + r) * 512 + dt * 64 + col] = hv;
    }
    __syncthreads();
    for (int c = tid; c < 4096; c += 256) {
        int rr = c >> 6, cc = c & 63;
        XT[(b * 512 + dt * 64 + rr) * 256 + kt * 64 + cc] = tile[cc][rr];
    }
}

// ---------- K1: fused pair-GEMM + tanh + att_weight + mask + softmax (MFMA) ----------
__launch_bounds__(256, 2)
__global__ void k1_att(const u16* __restrict__ Xbf, const float* __restrict__ xf,
                       const int* __restrict__ bnd,
                       const float* __restrict__ Wap, const float* __restrict__ bap,
                       const float* __restrict__ aw, u16* __restrict__ p_ws)
{
    const int b = blockIdx.x >> 8;
    const int j = blockIdx.x & 255;
    const int tid = threadIdx.x;
    const int w = tid >> 6;
    const int l = tid & 63;
    const int l15 = l & 15;
    const int lgp = l >> 4;

    __shared__ __align__(16) u16 XL[256 * 72];
    __shared__ __align__(16) u16 WL[64 * 72];
    __shared__ __align__(16) u16 awT[16 * 264];
    __shared__ float xj[512];
    __shared__ float attraw[256 * 9];
    __shared__ float maskv[256];
    __shared__ float biasf[256];
    __shared__ int scanv[256];

    const u16* xb = Xbf + b * (T_ * D_);
    const float* xjp = xf + (b * T_ + j) * D_;
    for (int i = tid; i < D_; i += 256) xj[i] = xjp[i];
    for (int i = tid; i < O_; i += 256) biasf[i] = bap[i];
    for (int i = tid; i < 16 * 264; i += 256) awT[i] = 0;
    scanv[tid] = bnd[b * T_ + tid];
    __syncthreads();
    for (int i = tid; i < O_ * H_; i += 256) {
        int o = i >> 3, h = i & 7;
        awT[h * 264 + o] = f2b(aw[i]);
    }
    for (int off = 1; off < 256; off <<= 1) {
        int v = (tid >= off) ? scanv[tid - off] : 0;
        __syncthreads();
        scanv[tid] += v;
        __syncthreads();
    }
    {
        int k = tid;
        float m;
        if (k == j) m = 1.f;
        else if (k > j) m = ((scanv[k] - (j ? scanv[j - 1] : 0)) == 0) ? 1.f : 0.f;
        else m = ((scanv[j] - (k ? scanv[k - 1] : 0)) == 0) ? 1.f : 0.f;
        maskv[k] = m;
    }

    f32x4 attacc[4] = {};

    for (int oc = 0; oc < 4; ++oc) {
        f32x4 acc[4][4] = {};
        for (int d0 = 0; d0 < D_; d0 += 64) {
            __syncthreads();
            #pragma unroll
            for (int c = 0; c < 8; ++c) {
                int cc = tid + c * 256;
                int r = cc >> 3, s = cc & 7;
                *reinterpret_cast<uint4*>(&XL[r * 72 + s * 8]) =
                    *reinterpret_cast<const uint4*>(xb + r * D_ + d0 + s * 8);
            }
            #pragma unroll
            for (int c = 0; c < 2; ++c) {
                int cc = tid + c * 256;
                int r = cc >> 3, s = cc & 7;
                const float* wp = Wap + (oc * 64 + r) * 512 + d0 + s * 8;
                f32x4 va = *reinterpret_cast<const f32x4*>(wp);
                f32x4 vb = *reinterpret_cast<const f32x4*>(wp + 4);
                const float* xq = &xj[d0 + s * 8];
                u16 tmp[8];
                #pragma unroll
                for (int e = 0; e < 4; ++e) tmp[e] = f2b(va[e] * xq[e]);
                #pragma unroll
                for (int e = 0; e < 4; ++e) tmp[4 + e] = f2b(vb[e] * xq[4 + e]);
                *reinterpret_cast<uint4*>(&WL[r * 72 + s * 8]) =
                    *reinterpret_cast<const uint4*>(tmp);
            }
            __syncthreads();
            #pragma unroll
            for (int ds = 0; ds < 2; ++ds) {
                bf16x8 bfr[4];
                #pragma unroll
                for (int ot = 0; ot < 4; ++ot)
                    bfr[ot] = *reinterpret_cast<const bf16x8*>(&WL[(ot * 16 + l15) * 72 + ds * 32 + lgp * 8]);
                #pragma unroll
                for (int kt = 0; kt < 4; ++kt) {
                    bf16x8 afr = *reinterpret_cast<const bf16x8*>(&XL[(w * 64 + kt * 16 + l15) * 72 + ds * 32 + lgp * 8]);
                    #pragma unroll
                    for (int ot = 0; ot < 4; ++ot)
                        acc[kt][ot] = __builtin_amdgcn_mfma_f32_16x16x32_bf16(afr, bfr[ot], acc[kt][ot], 0, 0, 0);
                }
            }
        }
        u16* a_lds = XL;
        #pragma unroll
        for (int kt = 0; kt < 4; ++kt)
            #pragma unroll
            for (int ot = 0; ot < 4; ++ot)
                #pragma unroll
                for (int i = 0; i < 4; ++i) {
                    int k = w * 64 + kt * 16 + lgp * 4 + i;
                    int ol = ot * 16 + l15;
                    float s = acc[kt][ot][i] + biasf[oc * 64 + ol];
                    a_lds[k * 72 + ol] = f2b(fast_tanh(s));
                }
        #pragma unroll
        for (int ds = 0; ds < 2; ++ds) {
            bf16x8 bw = *reinterpret_cast<const bf16x8*>(&awT[l15 * 264 + oc * 64 + ds * 32 + lgp * 8]);
            #pragma unroll
            for (int kt = 0; kt < 4; ++kt) {
                bf16x8 af = *reinterpret_cast<const bf16x8*>(&a_lds[(w * 64 + kt * 16 + l15) * 72 + ds * 32 + lgp * 8]);
                attacc[kt] = __builtin_amdgcn_mfma_f32_16x16x32_bf16(af, bw, attacc[kt], 0, 0, 0);
            }
        }
    }

    #pragma unroll
    for (int kt = 0; kt < 4; ++kt) {
        if (l15 < 8) {
            #pragma unroll
            for (int i = 0; i < 4; ++i) {
                int k = w * 64 + kt * 16 + lgp * 4 + i;
                attraw[k * 9 + l15] = attacc[kt][i];
            }
        }
    }
    __syncthreads();

    {
        int h = tid >> 5, c = tid & 31;
        float lgv[8];
        float mx = -3.4e38f;
        #pragma unroll
        for (int kk = 0; kk < 8; ++kk) {
            int k = c + kk * 32;
            float v = attraw[k * 9 + h] * maskv[k];
            lgv[kk] = v;
            mx = fmaxf(mx, v);
        }
        #pragma unroll
        for (int off = 1; off < 32; off <<= 1)
            mx = fmaxf(mx, __shfl_xor(mx, off, 32));
        float sum = 0.f;
        #pragma unroll
        for (int kk = 0; kk < 8; ++kk) {
            lgv[kk] = __expf(lgv[kk] - mx);
            sum += lgv[kk];
        }
        #pragma unroll
        for (int off = 1; off < 32; off <<= 1)
            sum += __shfl_xor(sum, off, 32);
        float inv = 1.f / sum;
        u16* dst = p_ws + (((b * 8 + h) * 256 + j) * 256);
        #pragma unroll
        for (int kk = 0; kk < 8; ++kk)
            dst[c + kk * 32] = f2b(lgv[kk] * inv);
    }
}

// ---------- K2: x1[b][j][d*8+h] = sum_k p[b,h,j,k] * x[b,k,d] (MFMA) ----------
__launch_bounds__(256, 2)
__global__ void k2_agg(const u16* __restrict__ p_ws, const u16* __restrict__ XT,
                       u16* __restrict__ x1)
{
    const int bh = blockIdx.x >> 3;
    const int dc = blockIdx.x & 7;
    const int b = bh >> 3;
    const int h = bh & 7;
    const int tid = threadIdx.x;
    const int w = tid >> 6, l = tid & 63, l15 = l & 15, lgp = l >> 4;

    __shared__ __align__(16) u16 AL[256 * 72];
    __shared__ __align__(16) u16 BL[64 * 72];

    const u16* A = p_ws + bh * (256 * 256);
    const u16* Bx = XT + (b * 512 + dc * 64) * 256;

    f32x4 acc[4][4] = {};
    for (int k0 = 0; k0 < 256; k0 += 64) {
        __syncthreads();
        #pragma unroll
        for (int c = 0; c < 8; ++c) {
            int cc = tid + c * 256;
            int r = cc >> 3, s = cc & 7;
            *reinterpret_cast<uint4*>(&AL[r * 72 + s * 8]) =
                *reinterpret_cast<const uint4*>(A + r * 256 + k0 + s * 8);
        }
        #pragma unroll
        for (int c = 0; c < 2; ++c) {
            int cc = tid + c * 256;
            int r = cc >> 3, s = cc & 7;
            *reinterpret_cast<uint4*>(&BL[r * 72 + s * 8]) =
                *reinterpret_cast<const uint4*>(Bx + r * 256 + k0 + s * 8);
        }
        __syncthreads();
        #pragma unroll
        for (int ds = 0; ds < 2; ++ds) {
            bf16x8 bfr[4];
            #pragma unroll
            for (int ot = 0; ot < 4; ++ot)
                bfr[ot] = *reinterpret_cast<const bf16x8*>(&BL[(ot * 16 + l15) * 72 + ds * 32 + lgp * 8]);
            #pragma unroll
            for (int kt = 0; kt < 4; ++kt) {
                bf16x8 afr = *reinterpret_cast<const bf16x8*>(&AL[(w * 64 + kt * 16 + l15) * 72 + ds * 32 + lgp * 8]);
                #pragma unroll
                for (int ot = 0; ot < 4; ++ot)
                    acc[kt][ot] = __builtin_amdgcn_mfma_f32_16x16x32_bf16(afr, bfr[ot], acc[kt][ot], 0, 0, 0);
            }
        }
    }
    #pragma unroll
    for (int kt = 0; kt < 4; ++kt)
        #pragma unroll
        for (int ot = 0; ot < 4; ++ot)
            #pragma unroll
            for (int i = 0; i < 4; ++i) {
                int jj = w * 64 + kt * 16 + lgp * 4 + i;
                int d = dc * 64 + ot * 16 + l15;
                x1[(b * 256 + jj) * 4096 + d * 8 + h] = f2b(acc[kt][ot][i]);
            }
}

// ---------- K3: split-K projections -> 5 partial buffers ----------
// grid 160: gid<128 -> GEMM1 (x1 @ W2^T, K=4096, 4 K-chunks of 1024)
//           gid>=128 -> GEMM2 (x @ W3^T, K=512) into part slot 4.
// Row index R = b*256+j in 0..511; 8 row tiles of 64; 4 col tiles of 64.
__launch_bounds__(256, 4)
__global__ void k3_mm(const u16* __restrict__ x1, const float* __restrict__ x,
                      const float* __restrict__ W2, const float* __restrict__ W3,
                      float* __restrict__ part)
{
    const int gid = blockIdx.x;
    const int tid = threadIdx.x;
    const int w = tid >> 6, l = tid & 63, l15 = l & 15, lgp = l >> 4;

    __shared__ __align__(16) u16 AL[64 * 72];
    __shared__ __align__(16) u16 BL[64 * 72];

    f32x4 acc[4] = {};
    int jc, oc, slot;
    if (gid < 128) {
        int kc = gid & 3;
        oc = (gid >> 2) & 3;
        jc = gid >> 4;
        slot = kc;
        const int j0 = jc * 64, o0 = oc * 64;
        const int tbeg = kc * 1024, tend = tbeg + 1024;
        for (int t0 = tbeg; t0 < tend; t0 += 64) {
            __syncthreads();
            #pragma unroll
            for (int c = 0; c < 2; ++c) {
                int cc = tid + c * 256;
                int r = cc >> 3, s = cc & 7;
                *reinterpret_cast<uint4*>(&AL[r * 72 + s * 8]) =
                    *reinterpret_cast<const uint4*>(x1 + (size_t)(j0 + r) * 4096 + t0 + s * 8);
                *reinterpret_cast<uint4*>(&BL[r * 72 + s * 8]) =
                    ld8f2b(W2 + (size_t)(o0 + r) * 4096 + t0 + s * 8);
            }
            __syncthreads();
            #pragma unroll
            for (int ds = 0; ds < 2; ++ds) {
                bf16x8 afr = *reinterpret_cast<const bf16x8*>(&AL[(w * 16 + l15) * 72 + ds * 32 + lgp * 8]);
                #pragma unroll
                for (int ot = 0; ot < 4; ++ot) {
                    bf16x8 bfr = *reinterpret_cast<const bf16x8*>(&BL[(ot * 16 + l15) * 72 + ds * 32 + lgp * 8]);
                    acc[ot] = __builtin_amdgcn_mfma_f32_16x16x32_bf16(afr, bfr, acc[ot], 0, 0, 0);
                }
            }
        }
    } else {
        int g2 = gid - 128;
        oc = g2 & 3;
        jc = g2 >> 2;
        slot = 4;
        const int j0 = jc * 64, o0 = oc * 64;
        for (int t0 = 0; t0 < 512; t0 += 64) {
            __syncthreads();
            #pragma unroll
            for (int c = 0; c < 2; ++c) {
                int cc = tid + c * 256;
                int r = cc >> 3, s = cc & 7;
                *reinterpret_cast<uint4*>(&AL[r * 72 + s * 8]) =
                    ld8f2b(x + (size_t)(j0 + r) * 512 + t0 + s * 8);
                *reinterpret_cast<uint4*>(&BL[r * 72 + s * 8]) =
                    ld8f2b(W3 + (size_t)(o0 + r) * 512 + t0 + s * 8);
            }
            __syncthreads();
            #pragma unroll
            for (int ds = 0; ds < 2; ++ds) {
                bf16x8 afr = *reinterpret_cast<const bf16x8*>(&AL[(w * 16 + l15) * 72 + ds * 32 + lgp * 8]);
                #pragma unroll
                for (int ot = 0; ot < 4; ++ot) {
                    bf16x8 bfr = *reinterpret_cast<const bf16x8*>(&BL[(ot * 16 + l15) * 72 + ds * 32 + lgp * 8]);
                    acc[ot] = __builtin_amdgcn_mfma_f32_16x16x32_bf16(afr, bfr, acc[ot], 0, 0, 0);
                }
            }
        }
    }
    const int j0 = jc * 64, o0 = oc * 64;
    float* dst = part + (size_t)slot * 512 * 256;
    #pragma unroll
    for (int ot = 0; ot < 4; ++ot)
        #pragma unroll
        for (int i = 0; i < 4; ++i) {
            int rr = j0 + w * 16 + lgp * 4 + i;
            int o = o0 + ot * 16 + l15;
            dst[rr * 256 + o] = acc[ot][i];
        }
}

// ---------- K4a: combine partials + biases -> ypre, and per-chunk BN stats ----------
__global__ void k4a_comb(const float* __restrict__ part,
                         const float* __restrict__ pb2, const float* __restrict__ pb3,
                         float* __restrict__ ypre,
                         float* __restrict__ psum, float* __restrict__ psq)
{
    int g = blockIdx.x, o = threadIdx.x;  // 64 blocks x 8 rows
    float bsum = pb2[o] + pb3[o];
    float s = 0.f, q = 0.f;
    for (int r = g * 8; r < g * 8 + 8; ++r) {
        size_t idx = (size_t)r * 256 + o;
        float v = part[idx] + part[131072 + idx] + part[2 * 131072 + idx]
                + part[3 * 131072 + idx] + part[4 * 131072 + idx] + bsum;
        ypre[idx] = v;
        s += v; q += v * v;
    }
    psum[g * 256 + o] = s;
    psq[g * 256 + o] = q;
}

// ---------- K4b: stats-reduce + normalize + affine + SELU -> FP32 output ----------
__global__ void k4b_norm(const float* __restrict__ ypre,
                         const float* __restrict__ psum, const float* __restrict__ psq,
                         const float* __restrict__ gamma, const float* __restrict__ beta,
                         float* __restrict__ out) {
    int r = blockIdx.x, o = threadIdx.x;  // 512 blocks x 256 threads
    float s = 0.f, q = 0.f;
    for (int g = 0; g < 64; ++g) {
        s += psum[g * 256 + o];
        q += psq[g * 256 + o];
    }
    float mu = s * (1.f / 512.f);
    float var = q * (1.f / 512.f) - mu * mu;
    float inv = rsqrtf(var + 1e-5f);
    float v = (ypre[r * 256 + o] - mu) * inv * gamma[o] + beta[o];
    const float SC = 1.0507009873554805f, AL = 1.6732632423543772f;
    float ov = v > 0.f ? SC * v : SC * AL * (__expf(v) - 1.f);
    out[r * 256 + o] = ov;
}

extern "C" void kernel_launch(void* const* d_in, const int* in_sizes, int n_in,
                              void* d_out, int out_size, void* d_ws, size_t ws_size,
                              hipStream_t stream) {
    const float* x    = (const float*)d_in[0];
    const int* bnd    = (const int*)d_in[1];
    const float* Wap  = (const float*)d_in[2];
    const float* bap  = (const float*)d_in[3];
    const float* aw   = (const float*)d_in[4];
    const float* W2   = (const float*)d_in[5];
    const float* pb2  = (const float*)d_in[6];
    const float* W3   = (const float*)d_in[7];
    const float* pb3  = (const float*)d_in[8];
    const float* gamma = (const float*)d_in[9];
    const float* beta  = (const float*)d_in[10];
    float* out = (float*)d_out;
    (void)in_sizes; (void)n_in; (void)out_size; (void)ws_size;

    char* ws = (char*)d_ws;
    u16* Xbf   = (u16*)ws;  ws += (size_t)B_ * T_ * D_ * 2;        // 512 KB
    u16* XT    = (u16*)ws;  ws += (size_t)B_ * D_ * T_ * 2;        // 512 KB
    u16* p_ws  = (u16*)ws;  ws += (size_t)B_ * H_ * T_ * T_ * 2;   // 2 MB
    u16* x1    = (u16*)ws;  ws += (size_t)B_ * T_ * D_ * H_ * 2;   // 4 MB
    float* part = (float*)ws; ws += (size_t)5 * 512 * 256 * 4;     // 2.6 MB
    float* ypre = (float*)ws; ws += (size_t)B_ * T_ * O_ * 4;      // 512 KB
    float* psum = (float*)ws; ws += (size_t)64 * O_ * 4;
    float* psq  = (float*)ws; ws += (size_t)64 * O_ * 4;

    k0_convert<<<64, 256, 0, stream>>>(x, Xbf, XT);
    k1_att<<<512, 256, 0, stream>>>(Xbf, x, bnd, Wap, bap, aw, p_ws);
    k2_agg<<<128, 256, 0, stream>>>(p_ws, XT, x1);
    k3_mm<<<160, 256, 0, stream>>>(x1, x, W2, W3, part);
    k4a_comb<<<64, 256, 0, stream>>>(part, pb2, pb3, ypre, psum, psq);
    k4b_norm<<<512, 256, 0, stream>>>(ypre, psum, psq, gamma, beta, out);
}

// Round 8
// 120.865 us; speedup vs baseline: 12.7179x; 1.0057x over previous
//
#include <hip/hip_runtime.h>
#include <hip/hip_bf16.h>

// Problem: B=2, T=256, IN_DIM=512, OUT_DIM=256, H=8, TEMP=1, BN_EPS=1e-5
// Device dtypes: inputs fp32 (boundary int32), OUTPUT fp32.
// ROUND 8: k1 v2 — swapped MFMA operands (C'[o][k]) so tanh epilogue writes
// packed b64 instead of 256 scalar b16 ds_writes; vectorized bias loads;
// k4 stats folded once (k4c).
#define B_ 2
#define T_ 256
#define D_ 512
#define O_ 256
#define H_ 8

typedef __attribute__((ext_vector_type(4))) float f32x4;
typedef __attribute__((ext_vector_type(8))) short bf16x8;
typedef unsigned short u16;
typedef unsigned int u32;

__device__ __forceinline__ float b2f(u16 u) {
    u32 t = ((u32)u) << 16;
    return __builtin_bit_cast(float, t);
}
__device__ __forceinline__ u16 f2b(float f) {
    u32 u = __builtin_bit_cast(u32, f);
    u32 r = (u + 0x7FFFu + ((u >> 16) & 1u)) >> 16;  // RNE
    return (u16)r;
}
__device__ __forceinline__ float fast_tanh(float x) {
    float ax = fabsf(x);
    float e = __expf(-2.f * ax);
    float r = (1.f - e) / (1.f + e);
    return x < 0.f ? -r : r;
}
__device__ __forceinline__ uint4 ld8f2b(const float* __restrict__ p) {
    f32x4 a = *reinterpret_cast<const f32x4*>(p);
    f32x4 b = *reinterpret_cast<const f32x4*>(p + 4);
    u16 t[8] = {f2b(a[0]), f2b(a[1]), f2b(a[2]), f2b(a[3]),
                f2b(b[0]), f2b(b[1]), f2b(b[2]), f2b(b[3])};
    return *reinterpret_cast<uint4*>(t);
}

// ---------- K0: Xbf[b][k][d] = bf16(x), XT[b][d][k] = bf16(x[b][k][d]) ----------
__global__ void k0_convert(const float* __restrict__ x,
                           u16* __restrict__ Xbf, u16* __restrict__ XT) {
    int idx = blockIdx.x;
    int dt = idx & 7, kt = (idx >> 3) & 3, b = idx >> 5;
    __shared__ u16 tile[64][65];
    int tid = threadIdx.x;
    for (int c = tid; c < 4096; c += 256) {
        int r = c >> 6, col = c & 63;
        float v = x[(b * 256 + kt * 64 + r) * 512 + dt * 64 + col];
        u16 hv = f2b(v);
        tile[r][col] = hv;
        Xbf[(b * 256 + kt * 64 + r) * 512 + dt * 64 + col] = hv;
    }
    __syncthreads();
    for (int c = tid; c < 4096; c += 256) {
        int rr = c >> 6, cc = c & 63;
        XT[(b * 512 + dt * 64 + rr) * 256 + kt * 64 + cc] = tile[cc][rr];
    }
}

// ---------- K1 v2: fused pair-GEMM + tanh + att_weight + mask + softmax ----------
__launch_bounds__(256, 2)
__global__ void k1_att(const u16* __restrict__ Xbf, const float* __restrict__ xf,
                       const int* __restrict__ bnd,
                       const float* __restrict__ Wap, const float* __restrict__ bap,
                       const float* __restrict__ aw, u16* __restrict__ p_ws)
{
    const int b = blockIdx.x >> 8;
    const int j = blockIdx.x & 255;
    const int tid = threadIdx.x;
    const int w = tid >> 6;
    const int l = tid & 63;
    const int l15 = l & 15;
    const int lgp = l >> 4;

    __shared__ __align__(16) u16 XL[256 * 72];   // X tile (k x 64d); reused as a_lds[k][o_local]
    __shared__ __align__(16) u16 WL[64 * 72];    // Wj tile (o_local x 64d)
    __shared__ __align__(16) u16 awT[16 * 264];  // att_weight^T [h][o], rows 8..15 zero
    __shared__ float xj[512];
    __shared__ float attraw[256 * 9];            // [k][h] pad 9
    __shared__ float maskv[256];
    __shared__ float biasf[256];
    __shared__ int scanv[256];

    const u16* xb = Xbf + b * (T_ * D_);
    const float* xjp = xf + (b * T_ + j) * D_;
    for (int i = tid; i < D_; i += 256) xj[i] = xjp[i];
    for (int i = tid; i < O_; i += 256) biasf[i] = bap[i];
    for (int i = tid; i < 16 * 264; i += 256) awT[i] = 0;
    scanv[tid] = bnd[b * T_ + tid];
    __syncthreads();
    for (int i = tid; i < O_ * H_; i += 256) {
        int o = i >> 3, h = i & 7;
        awT[h * 264 + o] = f2b(aw[i]);
    }
    for (int off = 1; off < 256; off <<= 1) {
        int v = (tid >= off) ? scanv[tid - off] : 0;
        __syncthreads();
        scanv[tid] += v;
        __syncthreads();
    }
    {
        int k = tid;
        float m;
        if (k == j) m = 1.f;
        else if (k > j) m = ((scanv[k] - (j ? scanv[j - 1] : 0)) == 0) ? 1.f : 0.f;
        else m = ((scanv[j] - (k ? scanv[k - 1] : 0)) == 0) ? 1.f : 0.f;
        maskv[k] = m;
    }

    f32x4 attacc[4] = {};  // att[k][h] accumulator frags (rows k, cols h)

    for (int oc = 0; oc < 4; ++oc) {
        f32x4 acc[4][4] = {};              // C'[o,k] tiles [ot][kt]
        for (int d0 = 0; d0 < D_; d0 += 64) {
            __syncthreads();
            #pragma unroll
            for (int c = 0; c < 8; ++c) {
                int cc = tid + c * 256;
                int r = cc >> 3, s = cc & 7;
                *reinterpret_cast<uint4*>(&XL[r * 72 + s * 8]) =
                    *reinterpret_cast<const uint4*>(xb + r * D_ + d0 + s * 8);
            }
            #pragma unroll
            for (int c = 0; c < 2; ++c) {
                int cc = tid + c * 256;
                int r = cc >> 3, s = cc & 7;
                const float* wp = Wap + (oc * 64 + r) * 512 + d0 + s * 8;
                f32x4 va = *reinterpret_cast<const f32x4*>(wp);
                f32x4 vb = *reinterpret_cast<const f32x4*>(wp + 4);
                const float* xq = &xj[d0 + s * 8];
                u16 tmp[8];
                #pragma unroll
                for (int e = 0; e < 4; ++e) tmp[e] = f2b(va[e] * xq[e]);
                #pragma unroll
                for (int e = 0; e < 4; ++e) tmp[4 + e] = f2b(vb[e] * xq[4 + e]);
                *reinterpret_cast<uint4*>(&WL[r * 72 + s * 8]) =
                    *reinterpret_cast<const uint4*>(tmp);
            }
            __syncthreads();
            // C'[o,k] += Wj · X^T  (A = W rows o, B = X rows k)
            #pragma unroll
            for (int ds = 0; ds < 2; ++ds) {
                bf16x8 wfr[4];
                #pragma unroll
                for (int ot = 0; ot < 4; ++ot)
                    wfr[ot] = *reinterpret_cast<const bf16x8*>(&WL[(ot * 16 + l15) * 72 + ds * 32 + lgp * 8]);
                #pragma unroll
                for (int kt = 0; kt < 4; ++kt) {
                    bf16x8 xfr = *reinterpret_cast<const bf16x8*>(&XL[(w * 64 + kt * 16 + l15) * 72 + ds * 32 + lgp * 8]);
                    #pragma unroll
                    for (int ot = 0; ot < 4; ++ot)
                        acc[ot][kt] = __builtin_amdgcn_mfma_f32_16x16x32_bf16(wfr[ot], xfr, acc[ot][kt], 0, 0, 0);
                }
            }
        }
        // tanh(s + bias) -> a_lds[k][o_local]; lane holds 4 consecutive o at fixed k
        u16* a_lds = XL;
        #pragma unroll
        for (int ot = 0; ot < 4; ++ot) {
            f32x4 bv = *reinterpret_cast<const f32x4*>(&biasf[oc * 64 + ot * 16 + lgp * 4]);
            #pragma unroll
            for (int kt = 0; kt < 4; ++kt) {
                int k = w * 64 + kt * 16 + l15;
                int obase = ot * 16 + lgp * 4;
                u16 t0 = f2b(fast_tanh(acc[ot][kt][0] + bv[0]));
                u16 t1 = f2b(fast_tanh(acc[ot][kt][1] + bv[1]));
                u16 t2 = f2b(fast_tanh(acc[ot][kt][2] + bv[2]));
                u16 t3 = f2b(fast_tanh(acc[ot][kt][3] + bv[3]));
                uint2 pk;
                pk.x = (u32)t0 | ((u32)t1 << 16);
                pk.y = (u32)t2 | ((u32)t3 << 16);
                *reinterpret_cast<uint2*>(&a_lds[k * 72 + obase]) = pk;
            }
        }
        // att[k,h] += a[k, o-chunk] · awT[h, o-chunk]^T  (wave-local rows; lgkmcnt dep)
        #pragma unroll
        for (int ds = 0; ds < 2; ++ds) {
            bf16x8 bw = *reinterpret_cast<const bf16x8*>(&awT[l15 * 264 + oc * 64 + ds * 32 + lgp * 8]);
            #pragma unroll
            for (int kt = 0; kt < 4; ++kt) {
                bf16x8 af = *reinterpret_cast<const bf16x8*>(&a_lds[(w * 64 + kt * 16 + l15) * 72 + ds * 32 + lgp * 8]);
                attacc[kt] = __builtin_amdgcn_mfma_f32_16x16x32_bf16(af, bw, attacc[kt], 0, 0, 0);
            }
        }
    }

    #pragma unroll
    for (int kt = 0; kt < 4; ++kt) {
        if (l15 < 8) {
            #pragma unroll
            for (int i = 0; i < 4; ++i) {
                int k = w * 64 + kt * 16 + lgp * 4 + i;
                attraw[k * 9 + l15] = attacc[kt][i];
            }
        }
    }
    __syncthreads();

    {
        int h = tid >> 5, c = tid & 31;
        float lgv[8];
        float mx = -3.4e38f;
        #pragma unroll
        for (int kk = 0; kk < 8; ++kk) {
            int k = c + kk * 32;
            float v = attraw[k * 9 + h] * maskv[k];
            lgv[kk] = v;
            mx = fmaxf(mx, v);
        }
        #pragma unroll
        for (int off = 1; off < 32; off <<= 1)
            mx = fmaxf(mx, __shfl_xor(mx, off, 32));
        float sum = 0.f;
        #pragma unroll
        for (int kk = 0; kk < 8; ++kk) {
            lgv[kk] = __expf(lgv[kk] - mx);
            sum += lgv[kk];
        }
        #pragma unroll
        for (int off = 1; off < 32; off <<= 1)
            sum += __shfl_xor(sum, off, 32);
        float inv = 1.f / sum;
        u16* dst = p_ws + (((b * 8 + h) * 256 + j) * 256);
        #pragma unroll
        for (int kk = 0; kk < 8; ++kk)
            dst[c + kk * 32] = f2b(lgv[kk] * inv);
    }
}

// ---------- K2: x1[b][j][d*8+h] = sum_k p[b,h,j,k] * x[b,k,d] (MFMA) ----------
__launch_bounds__(256, 2)
__global__ void k2_agg(const u16* __restrict__ p_ws, const u16* __restrict__ XT,
                       u16* __restrict__ x1)
{
    const int bh = blockIdx.x >> 3;
    const int dc = blockIdx.x & 7;
    const int b = bh >> 3;
    const int h = bh & 7;
    const int tid = threadIdx.x;
    const int w = tid >> 6, l = tid & 63, l15 = l & 15, lgp = l >> 4;

    __shared__ __align__(16) u16 AL[256 * 72];
    __shared__ __align__(16) u16 BL[64 * 72];

    const u16* A = p_ws + bh * (256 * 256);
    const u16* Bx = XT + (b * 512 + dc * 64) * 256;

    f32x4 acc[4][4] = {};
    for (int k0 = 0; k0 < 256; k0 += 64) {
        __syncthreads();
        #pragma unroll
        for (int c = 0; c < 8; ++c) {
            int cc = tid + c * 256;
            int r = cc >> 3, s = cc & 7;
            *reinterpret_cast<uint4*>(&AL[r * 72 + s * 8]) =
                *reinterpret_cast<const uint4*>(A + r * 256 + k0 + s * 8);
        }
        #pragma unroll
        for (int c = 0; c < 2; ++c) {
            int cc = tid + c * 256;
            int r = cc >> 3, s = cc & 7;
            *reinterpret_cast<uint4*>(&BL[r * 72 + s * 8]) =
                *reinterpret_cast<const uint4*>(Bx + r * 256 + k0 + s * 8);
        }
        __syncthreads();
        #pragma unroll
        for (int ds = 0; ds < 2; ++ds) {
            bf16x8 bfr[4];
            #pragma unroll
            for (int ot = 0; ot < 4; ++ot)
                bfr[ot] = *reinterpret_cast<const bf16x8*>(&BL[(ot * 16 + l15) * 72 + ds * 32 + lgp * 8]);
            #pragma unroll
            for (int kt = 0; kt < 4; ++kt) {
                bf16x8 afr = *reinterpret_cast<const bf16x8*>(&AL[(w * 64 + kt * 16 + l15) * 72 + ds * 32 + lgp * 8]);
                #pragma unroll
                for (int ot = 0; ot < 4; ++ot)
                    acc[kt][ot] = __builtin_amdgcn_mfma_f32_16x16x32_bf16(afr, bfr[ot], acc[kt][ot], 0, 0, 0);
            }
        }
    }
    #pragma unroll
    for (int kt = 0; kt < 4; ++kt)
        #pragma unroll
        for (int ot = 0; ot < 4; ++ot)
            #pragma unroll
            for (int i = 0; i < 4; ++i) {
                int jj = w * 64 + kt * 16 + lgp * 4 + i;
                int d = dc * 64 + ot * 16 + l15;
                x1[(b * 256 + jj) * 4096 + d * 8 + h] = f2b(acc[kt][ot][i]);
            }
}

// ---------- K3: split-K projections -> 5 partial buffers ----------
__launch_bounds__(256, 4)
__global__ void k3_mm(const u16* __restrict__ x1, const float* __restrict__ x,
                      const float* __restrict__ W2, const float* __restrict__ W3,
                      float* __restrict__ part)
{
    const int gid = blockIdx.x;
    const int tid = threadIdx.x;
    const int w = tid >> 6, l = tid & 63, l15 = l & 15, lgp = l >> 4;

    __shared__ __align__(16) u16 AL[64 * 72];
    __shared__ __align__(16) u16 BL[64 * 72];

    f32x4 acc[4] = {};
    int jc, oc, slot;
    if (gid < 128) {
        int kc = gid & 3;
        oc = (gid >> 2) & 3;
        jc = gid >> 4;
        slot = kc;
        const int j0 = jc * 64, o0 = oc * 64;
        const int tbeg = kc * 1024, tend = tbeg + 1024;
        for (int t0 = tbeg; t0 < tend; t0 += 64) {
            __syncthreads();
            #pragma unroll
            for (int c = 0; c < 2; ++c) {
                int cc = tid + c * 256;
                int r = cc >> 3, s = cc & 7;
                *reinterpret_cast<uint4*>(&AL[r * 72 + s * 8]) =
                    *reinterpret_cast<const uint4*>(x1 + (size_t)(j0 + r) * 4096 + t0 + s * 8);
                *reinterpret_cast<uint4*>(&BL[r * 72 + s * 8]) =
                    ld8f2b(W2 + (size_t)(o0 + r) * 4096 + t0 + s * 8);
            }
            __syncthreads();
            #pragma unroll
            for (int ds = 0; ds < 2; ++ds) {
                bf16x8 afr = *reinterpret_cast<const bf16x8*>(&AL[(w * 16 + l15) * 72 + ds * 32 + lgp * 8]);
                #pragma unroll
                for (int ot = 0; ot < 4; ++ot) {
                    bf16x8 bfr = *reinterpret_cast<const bf16x8*>(&BL[(ot * 16 + l15) * 72 + ds * 32 + lgp * 8]);
                    acc[ot] = __builtin_amdgcn_mfma_f32_16x16x32_bf16(afr, bfr, acc[ot], 0, 0, 0);
                }
            }
        }
    } else {
        int g2 = gid - 128;
        oc = g2 & 3;
        jc = g2 >> 2;
        slot = 4;
        const int j0 = jc * 64, o0 = oc * 64;
        for (int t0 = 0; t0 < 512; t0 += 64) {
            __syncthreads();
            #pragma unroll
            for (int c = 0; c < 2; ++c) {
                int cc = tid + c * 256;
                int r = cc >> 3, s = cc & 7;
                *reinterpret_cast<uint4*>(&AL[r * 72 + s * 8]) =
                    ld8f2b(x + (size_t)(j0 + r) * 512 + t0 + s * 8);
                *reinterpret_cast<uint4*>(&BL[r * 72 + s * 8]) =
                    ld8f2b(W3 + (size_t)(o0 + r) * 512 + t0 + s * 8);
            }
            __syncthreads();
            #pragma unroll
            for (int ds = 0; ds < 2; ++ds) {
                bf16x8 afr = *reinterpret_cast<const bf16x8*>(&AL[(w * 16 + l15) * 72 + ds * 32 + lgp * 8]);
                #pragma unroll
                for (int ot = 0; ot < 4; ++ot) {
                    bf16x8 bfr = *reinterpret_cast<const bf16x8*>(&BL[(ot * 16 + l15) * 72 + ds * 32 + lgp * 8]);
                    acc[ot] = __builtin_amdgcn_mfma_f32_16x16x32_bf16(afr, bfr, acc[ot], 0, 0, 0);
                }
            }
        }
    }
    const int j0 = jc * 64, o0 = oc * 64;
    float* dst = part + (size_t)slot * 512 * 256;
    #pragma unroll
    for (int ot = 0; ot < 4; ++ot)
        #pragma unroll
        for (int i = 0; i < 4; ++i) {
            int rr = j0 + w * 16 + lgp * 4 + i;
            int o = o0 + ot * 16 + l15;
            dst[rr * 256 + o] = acc[ot][i];
        }
}

// ---------- K4a: combine partials + biases -> ypre, per-chunk BN stats ----------
__global__ void k4a_comb(const float* __restrict__ part,
                         const float* __restrict__ pb2, const float* __restrict__ pb3,
                         float* __restrict__ ypre,
                         float* __restrict__ psum, float* __restrict__ psq)
{
    int g = blockIdx.x, o = threadIdx.x;  // 64 blocks x 8 rows
    float bsum = pb2[o] + pb3[o];
    float s = 0.f, q = 0.f;
    for (int r = g * 8; r < g * 8 + 8; ++r) {
        size_t idx = (size_t)r * 256 + o;
        float v = part[idx] + part[131072 + idx] + part[2 * 131072 + idx]
                + part[3 * 131072 + idx] + part[4 * 131072 + idx] + bsum;
        ypre[idx] = v;
        s += v; q += v * v;
    }
    psum[g * 256 + o] = s;
    psq[g * 256 + o] = q;
}

// ---------- K4c: fold 64-chunk stats -> mu, inv (1 block) ----------
__global__ void k4c_stats(const float* __restrict__ psum, const float* __restrict__ psq,
                          float* __restrict__ mu, float* __restrict__ inv) {
    int o = threadIdx.x;
    float s = 0.f, q = 0.f;
    for (int g = 0; g < 64; ++g) {
        s += psum[g * 256 + o];
        q += psq[g * 256 + o];
    }
    float m = s * (1.f / 512.f);
    float var = q * (1.f / 512.f) - m * m;
    mu[o] = m;
    inv[o] = rsqrtf(var + 1e-5f);
}

// ---------- K4b: normalize + affine + SELU -> FP32 output ----------
__global__ void k4b_norm(const float* __restrict__ ypre,
                         const float* __restrict__ mu, const float* __restrict__ inv,
                         const float* __restrict__ gamma, const float* __restrict__ beta,
                         float* __restrict__ out) {
    int r = blockIdx.x, o = threadIdx.x;  // 512 blocks x 256 threads
    float v = (ypre[r * 256 + o] - mu[o]) * inv[o] * gamma[o] + beta[o];
    const float SC = 1.0507009873554805f, AL = 1.6732632423543772f;
    float ov = v > 0.f ? SC * v : SC * AL * (__expf(v) - 1.f);
    out[r * 256 + o] = ov;
}

extern "C" void kernel_launch(void* const* d_in, const int* in_sizes, int n_in,
                              void* d_out, int out_size, void* d_ws, size_t ws_size,
                              hipStream_t stream) {
    const float* x    = (const float*)d_in[0];
    const int* bnd    = (const int*)d_in[1];
    const float* Wap  = (const float*)d_in[2];
    const float* bap  = (const float*)d_in[3];
    const float* aw   = (const float*)d_in[4];
    const float* W2   = (const float*)d_in[5];
    const float* pb2  = (const float*)d_in[6];
    const float* W3   = (const float*)d_in[7];
    const float* pb3  = (const float*)d_in[8];
    const float* gamma = (const float*)d_in[9];
    const float* beta  = (const float*)d_in[10];
    float* out = (float*)d_out;
    (void)in_sizes; (void)n_in; (void)out_size; (void)ws_size;

    char* ws = (char*)d_ws;
    u16* Xbf   = (u16*)ws;  ws += (size_t)B_ * T_ * D_ * 2;
    u16* XT    = (u16*)ws;  ws += (size_t)B_ * D_ * T_ * 2;
    u16* p_ws  = (u16*)ws;  ws += (size_t)B_ * H_ * T_ * T_ * 2;
    u16* x1    = (u16*)ws;  ws += (size_t)B_ * T_ * D_ * H_ * 2;
    float* part = (float*)ws; ws += (size_t)5 * 512 * 256 * 4;
    float* ypre = (float*)ws; ws += (size_t)B_ * T_ * O_ * 4;
    float* psum = (float*)ws; ws += (size_t)64 * O_ * 4;
    float* psq  = (float*)ws; ws += (size_t)64 * O_ * 4;
    float* muv  = (float*)ws; ws += (size_t)O_ * 4;
    float* invv = (float*)ws; ws += (size_t)O_ * 4;

    k0_convert<<<64, 256, 0, stream>>>(x, Xbf, XT);
    k1_att<<<512, 256, 0, stream>>>(Xbf, x, bnd, Wap, bap, aw, p_ws);
    k2_agg<<<128, 256, 0, stream>>>(p_ws, XT, x1);
    k3_mm<<<160, 256, 0, stream>>>(x1, x, W2, W3, part);
    k4a_comb<<<64, 256, 0, stream>>>(part, pb2, pb3, ypre, psum, psq);
    k4c_stats<<<1, 256, 0, stream>>>(psum, psq, muv, invv);
    k4b_norm<<<512, 256, 0, stream>>>(ypre, muv, invv, gamma, beta, out);
}

// Round 9
// 118.226 us; speedup vs baseline: 13.0018x; 1.0223x over previous
//
#include <hip/hip_runtime.h>
#include <hip/hip_bf16.h>

// Problem: B=2, T=256, IN_DIM=512, OUT_DIM=256, H=8, TEMP=1, BN_EPS=1e-5
// Device dtypes: inputs fp32 (boundary int32), OUTPUT fp32.
// ROUND 9: k1 v3 — X staging via global_load_lds (width=16) into unpadded
// XL[256][64] with XOR swizzle (col16 ^= row&7) applied on BOTH the global
// source address and all LDS reads/writes (m201 both-sides rule).
#define B_ 2
#define T_ 256
#define D_ 512
#define O_ 256
#define H_ 8

typedef __attribute__((ext_vector_type(4))) float f32x4;
typedef __attribute__((ext_vector_type(8))) short bf16x8;
typedef unsigned short u16;
typedef unsigned int u32;

__device__ __forceinline__ float b2f(u16 u) {
    u32 t = ((u32)u) << 16;
    return __builtin_bit_cast(float, t);
}
__device__ __forceinline__ u16 f2b(float f) {
    u32 u = __builtin_bit_cast(u32, f);
    u32 r = (u + 0x7FFFu + ((u >> 16) & 1u)) >> 16;  // RNE
    return (u16)r;
}
__device__ __forceinline__ float fast_tanh(float x) {
    float ax = fabsf(x);
    float e = __expf(-2.f * ax);
    float r = (1.f - e) / (1.f + e);
    return x < 0.f ? -r : r;
}
__device__ __forceinline__ uint4 ld8f2b(const float* __restrict__ p) {
    f32x4 a = *reinterpret_cast<const f32x4*>(p);
    f32x4 b = *reinterpret_cast<const f32x4*>(p + 4);
    u16 t[8] = {f2b(a[0]), f2b(a[1]), f2b(a[2]), f2b(a[3]),
                f2b(b[0]), f2b(b[1]), f2b(b[2]), f2b(b[3])};
    return *reinterpret_cast<uint4*>(t);
}
// async global->LDS, 16B per lane; dst = wave-uniform base + lane*16
__device__ __forceinline__ void gload16(const void* g, void* l) {
    __builtin_amdgcn_global_load_lds(
        (const __attribute__((address_space(1))) unsigned int*)g,
        (__attribute__((address_space(3))) unsigned int*)l, 16, 0, 0);
}

// ---------- K0: Xbf[b][k][d] = bf16(x), XT[b][d][k] = bf16(x[b][k][d]) ----------
__global__ void k0_convert(const float* __restrict__ x,
                           u16* __restrict__ Xbf, u16* __restrict__ XT) {
    int idx = blockIdx.x;
    int dt = idx & 7, kt = (idx >> 3) & 3, b = idx >> 5;
    __shared__ u16 tile[64][65];
    int tid = threadIdx.x;
    for (int c = tid; c < 4096; c += 256) {
        int r = c >> 6, col = c & 63;
        float v = x[(b * 256 + kt * 64 + r) * 512 + dt * 64 + col];
        u16 hv = f2b(v);
        tile[r][col] = hv;
        Xbf[(b * 256 + kt * 64 + r) * 512 + dt * 64 + col] = hv;
    }
    __syncthreads();
    for (int c = tid; c < 4096; c += 256) {
        int rr = c >> 6, cc = c & 63;
        XT[(b * 512 + dt * 64 + rr) * 256 + kt * 64 + cc] = tile[cc][rr];
    }
}

// ---------- K1 v3: fused pair-GEMM + tanh + att_weight + mask + softmax ----------
__launch_bounds__(256, 2)
__global__ void k1_att(const u16* __restrict__ Xbf, const float* __restrict__ xf,
                       const int* __restrict__ bnd,
                       const float* __restrict__ Wap, const float* __restrict__ bap,
                       const float* __restrict__ aw, u16* __restrict__ p_ws)
{
    const int b = blockIdx.x >> 8;
    const int j = blockIdx.x & 255;
    const int tid = threadIdx.x;
    const int w = tid >> 6;
    const int l = tid & 63;
    const int l15 = l & 15;
    const int lgp = l >> 4;

    // XL: unpadded 256 rows x 128B, XOR-swizzled (col16 ^= row&7). DMA dest.
    __shared__ __align__(16) u16 XL[256 * 64];   // 32 KB; reused as a_lds
    __shared__ __align__(16) u16 WL[64 * 72];    // Wj tile (o_local x 64d), pad 72
    __shared__ __align__(16) u16 awT[16 * 264];  // att_weight^T [h][o]
    __shared__ float xj[512];
    __shared__ float attraw[256 * 9];            // [k][h] pad 9
    __shared__ float maskv[256];
    __shared__ float biasf[256];
    __shared__ int scanv[256];

    const u16* xb = Xbf + b * (T_ * D_);
    const float* xjp = xf + (b * T_ + j) * D_;
    for (int i = tid; i < D_; i += 256) xj[i] = xjp[i];
    for (int i = tid; i < O_; i += 256) biasf[i] = bap[i];
    for (int i = tid; i < 16 * 264; i += 256) awT[i] = 0;
    scanv[tid] = bnd[b * T_ + tid];
    __syncthreads();
    for (int i = tid; i < O_ * H_; i += 256) {
        int o = i >> 3, h = i & 7;
        awT[h * 264 + o] = f2b(aw[i]);
    }
    for (int off = 1; off < 256; off <<= 1) {
        int v = (tid >= off) ? scanv[tid - off] : 0;
        __syncthreads();
        scanv[tid] += v;
        __syncthreads();
    }
    {
        int k = tid;
        float m;
        if (k == j) m = 1.f;
        else if (k > j) m = ((scanv[k] - (j ? scanv[j - 1] : 0)) == 0) ? 1.f : 0.f;
        else m = ((scanv[j] - (k ? scanv[k - 1] : 0)) == 0) ? 1.f : 0.f;
        maskv[k] = m;
    }

    // DMA source column pre-swizzle for this lane (constant across loop):
    const int srow_off = (l >> 3);            // row contribution of lane
    const int scol = ((l & 7) ^ ((l >> 3) & 7)) * 8;  // swizzled source col (u16)

    f32x4 attacc[4] = {};  // att[k][h] accumulator frags

    for (int oc = 0; oc < 4; ++oc) {
        f32x4 acc[4][4] = {};              // C'[o,k] tiles [ot][kt]
        for (int d0 = 0; d0 < D_; d0 += 64) {
            __syncthreads();
            // stage X tile via async DMA: issue i covers rows i*32+w*8+(l>>3)
            #pragma unroll
            for (int i = 0; i < 8; ++i) {
                int row = i * 32 + w * 8 + srow_off;
                gload16(xb + row * 512 + d0 + scol,
                        &XL[i * 2048 + w * 512]);
            }
            // stage W tile scaled by xj (fp32 math)
            #pragma unroll
            for (int c = 0; c < 2; ++c) {
                int cc = tid + c * 256;
                int r = cc >> 3, s = cc & 7;
                const float* wp = Wap + (oc * 64 + r) * 512 + d0 + s * 8;
                f32x4 va = *reinterpret_cast<const f32x4*>(wp);
                f32x4 vb = *reinterpret_cast<const f32x4*>(wp + 4);
                const float* xq = &xj[d0 + s * 8];
                u16 tmp[8];
                #pragma unroll
                for (int e = 0; e < 4; ++e) tmp[e] = f2b(va[e] * xq[e]);
                #pragma unroll
                for (int e = 0; e < 4; ++e) tmp[4 + e] = f2b(vb[e] * xq[4 + e]);
                *reinterpret_cast<uint4*>(&WL[r * 72 + s * 8]) =
                    *reinterpret_cast<const uint4*>(tmp);
            }
            __syncthreads();   // drains vmcnt (DMA) + lgkm
            // C'[o,k] += Wj · X^T   (A = W rows o, B = X rows k, swizzled read)
            #pragma unroll
            for (int ds = 0; ds < 2; ++ds) {
                bf16x8 wfr[4];
                #pragma unroll
                for (int ot = 0; ot < 4; ++ot)
                    wfr[ot] = *reinterpret_cast<const bf16x8*>(&WL[(ot * 16 + l15) * 72 + ds * 32 + lgp * 8]);
                #pragma unroll
                for (int kt = 0; kt < 4; ++kt) {
                    int row = w * 64 + kt * 16 + l15;
                    int c16 = ((ds * 4 + lgp) ^ (l15 & 7)) * 8;
                    bf16x8 xfr = *reinterpret_cast<const bf16x8*>(&XL[row * 64 + c16]);
                    #pragma unroll
                    for (int ot = 0; ot < 4; ++ot)
                        acc[ot][kt] = __builtin_amdgcn_mfma_f32_16x16x32_bf16(wfr[ot], xfr, acc[ot][kt], 0, 0, 0);
                }
            }
        }
        // tanh(s + bias) -> a_lds (aliases XL, same swizzle); own k-strip only
        u16* a_lds = XL;
        #pragma unroll
        for (int ot = 0; ot < 4; ++ot) {
            f32x4 bv = *reinterpret_cast<const f32x4*>(&biasf[oc * 64 + ot * 16 + lgp * 4]);
            #pragma unroll
            for (int kt = 0; kt < 4; ++kt) {
                int k = w * 64 + kt * 16 + l15;
                u16 t0 = f2b(fast_tanh(acc[ot][kt][0] + bv[0]));
                u16 t1 = f2b(fast_tanh(acc[ot][kt][1] + bv[1]));
                u16 t2 = f2b(fast_tanh(acc[ot][kt][2] + bv[2]));
                u16 t3 = f2b(fast_tanh(acc[ot][kt][3] + bv[3]));
                uint2 pk;
                pk.x = (u32)t0 | ((u32)t1 << 16);
                pk.y = (u32)t2 | ((u32)t3 << 16);
                int c16 = (ot * 2 + (lgp >> 1)) ^ (l15 & 7);
                *reinterpret_cast<uint2*>(&a_lds[k * 64 + c16 * 8 + (lgp & 1) * 4]) = pk;
            }
        }
        // att[k,h] += a[k, o-chunk] · awT[h, o-chunk]^T  (swizzled a_lds read)
        #pragma unroll
        for (int ds = 0; ds < 2; ++ds) {
            bf16x8 bw = *reinterpret_cast<const bf16x8*>(&awT[l15 * 264 + oc * 64 + ds * 32 + lgp * 8]);
            #pragma unroll
            for (int kt = 0; kt < 4; ++kt) {
                int row = w * 64 + kt * 16 + l15;
                int c16 = ((ds * 4 + lgp) ^ (l15 & 7)) * 8;
                bf16x8 af = *reinterpret_cast<const bf16x8*>(&a_lds[row * 64 + c16]);
                attacc[kt] = __builtin_amdgcn_mfma_f32_16x16x32_bf16(af, bw, attacc[kt], 0, 0, 0);
            }
        }
    }

    #pragma unroll
    for (int kt = 0; kt < 4; ++kt) {
        if (l15 < 8) {
            #pragma unroll
            for (int i = 0; i < 4; ++i) {
                int k = w * 64 + kt * 16 + lgp * 4 + i;
                attraw[k * 9 + l15] = attacc[kt][i];
            }
        }
    }
    __syncthreads();

    {
        int h = tid >> 5, c = tid & 31;
        float lgv[8];
        float mx = -3.4e38f;
        #pragma unroll
        for (int kk = 0; kk < 8; ++kk) {
            int k = c + kk * 32;
            float v = attraw[k * 9 + h] * maskv[k];
            lgv[kk] = v;
            mx = fmaxf(mx, v);
        }
        #pragma unroll
        for (int off = 1; off < 32; off <<= 1)
            mx = fmaxf(mx, __shfl_xor(mx, off, 32));
        float sum = 0.f;
        #pragma unroll
        for (int kk = 0; kk < 8; ++kk) {
            lgv[kk] = __expf(lgv[kk] - mx);
            sum += lgv[kk];
        }
        #pragma unroll
        for (int off = 1; off < 32; off <<= 1)
            sum += __shfl_xor(sum, off, 32);
        float inv = 1.f / sum;
        u16* dst = p_ws + (((b * 8 + h) * 256 + j) * 256);
        #pragma unroll
        for (int kk = 0; kk < 8; ++kk)
            dst[c + kk * 32] = f2b(lgv[kk] * inv);
    }
}

// ---------- K2: x1[b][j][d*8+h] = sum_k p[b,h,j,k] * x[b,k,d] (MFMA) ----------
__launch_bounds__(256, 2)
__global__ void k2_agg(const u16* __restrict__ p_ws, const u16* __restrict__ XT,
                       u16* __restrict__ x1)
{
    const int bh = blockIdx.x >> 3;
    const int dc = blockIdx.x & 7;
    const int b = bh >> 3;
    const int h = bh & 7;
    const int tid = threadIdx.x;
    const int w = tid >> 6, l = tid & 63, l15 = l & 15, lgp = l >> 4;

    __shared__ __align__(16) u16 AL[256 * 72];
    __shared__ __align__(16) u16 BL[64 * 72];

    const u16* A = p_ws + bh * (256 * 256);
    const u16* Bx = XT + (b * 512 + dc * 64) * 256;

    f32x4 acc[4][4] = {};
    for (int k0 = 0; k0 < 256; k0 += 64) {
        __syncthreads();
        #pragma unroll
        for (int c = 0; c < 8; ++c) {
            int cc = tid + c * 256;
            int r = cc >> 3, s = cc & 7;
            *reinterpret_cast<uint4*>(&AL[r * 72 + s * 8]) =
                *reinterpret_cast<const uint4*>(A + r * 256 + k0 + s * 8);
        }
        #pragma unroll
        for (int c = 0; c < 2; ++c) {
            int cc = tid + c * 256;
            int r = cc >> 3, s = cc & 7;
            *reinterpret_cast<uint4*>(&BL[r * 72 + s * 8]) =
                *reinterpret_cast<const uint4*>(Bx + r * 256 + k0 + s * 8);
        }
        __syncthreads();
        #pragma unroll
        for (int ds = 0; ds < 2; ++ds) {
            bf16x8 bfr[4];
            #pragma unroll
            for (int ot = 0; ot < 4; ++ot)
                bfr[ot] = *reinterpret_cast<const bf16x8*>(&BL[(ot * 16 + l15) * 72 + ds * 32 + lgp * 8]);
            #pragma unroll
            for (int kt = 0; kt < 4; ++kt) {
                bf16x8 afr = *reinterpret_cast<const bf16x8*>(&AL[(w * 64 + kt * 16 + l15) * 72 + ds * 32 + lgp * 8]);
                #pragma unroll
                for (int ot = 0; ot < 4; ++ot)
                    acc[kt][ot] = __builtin_amdgcn_mfma_f32_16x16x32_bf16(afr, bfr[ot], acc[kt][ot], 0, 0, 0);
            }
        }
    }
    #pragma unroll
    for (int kt = 0; kt < 4; ++kt)
        #pragma unroll
        for (int ot = 0; ot < 4; ++ot)
            #pragma unroll
            for (int i = 0; i < 4; ++i) {
                int jj = w * 64 + kt * 16 + lgp * 4 + i;
                int d = dc * 64 + ot * 16 + l15;
                x1[(b * 256 + jj) * 4096 + d * 8 + h] = f2b(acc[kt][ot][i]);
            }
}

// ---------- K3: split-K projections -> 5 partial buffers ----------
__launch_bounds__(256, 4)
__global__ void k3_mm(const u16* __restrict__ x1, const float* __restrict__ x,
                      const float* __restrict__ W2, const float* __restrict__ W3,
                      float* __restrict__ part)
{
    const int gid = blockIdx.x;
    const int tid = threadIdx.x;
    const int w = tid >> 6, l = tid & 63, l15 = l & 15, lgp = l >> 4;

    __shared__ __align__(16) u16 AL[64 * 72];
    __shared__ __align__(16) u16 BL[64 * 72];

    f32x4 acc[4] = {};
    int jc, oc, slot;
    if (gid < 128) {
        int kc = gid & 3;
        oc = (gid >> 2) & 3;
        jc = gid >> 4;
        slot = kc;
        const int j0 = jc * 64, o0 = oc * 64;
        const int tbeg = kc * 1024, tend = tbeg + 1024;
        for (int t0 = tbeg; t0 < tend; t0 += 64) {
            __syncthreads();
            #pragma unroll
            for (int c = 0; c < 2; ++c) {
                int cc = tid + c * 256;
                int r = cc >> 3, s = cc & 7;
                *reinterpret_cast<uint4*>(&AL[r * 72 + s * 8]) =
                    *reinterpret_cast<const uint4*>(x1 + (size_t)(j0 + r) * 4096 + t0 + s * 8);
                *reinterpret_cast<uint4*>(&BL[r * 72 + s * 8]) =
                    ld8f2b(W2 + (size_t)(o0 + r) * 4096 + t0 + s * 8);
            }
            __syncthreads();
            #pragma unroll
            for (int ds = 0; ds < 2; ++ds) {
                bf16x8 afr = *reinterpret_cast<const bf16x8*>(&AL[(w * 16 + l15) * 72 + ds * 32 + lgp * 8]);
                #pragma unroll
                for (int ot = 0; ot < 4; ++ot) {
                    bf16x8 bfr = *reinterpret_cast<const bf16x8*>(&BL[(ot * 16 + l15) * 72 + ds * 32 + lgp * 8]);
                    acc[ot] = __builtin_amdgcn_mfma_f32_16x16x32_bf16(afr, bfr, acc[ot], 0, 0, 0);
                }
            }
        }
    } else {
        int g2 = gid - 128;
        oc = g2 & 3;
        jc = g2 >> 2;
        slot = 4;
        const int j0 = jc * 64, o0 = oc * 64;
        for (int t0 = 0; t0 < 512; t0 += 64) {
            __syncthreads();
            #pragma unroll
            for (int c = 0; c < 2; ++c) {
                int cc = tid + c * 256;
                int r = cc >> 3, s = cc & 7;
                *reinterpret_cast<uint4*>(&AL[r * 72 + s * 8]) =
                    ld8f2b(x + (size_t)(j0 + r) * 512 + t0 + s * 8);
                *reinterpret_cast<uint4*>(&BL[r * 72 + s * 8]) =
                    ld8f2b(W3 + (size_t)(o0 + r) * 512 + t0 + s * 8);
            }
            __syncthreads();
            #pragma unroll
            for (int ds = 0; ds < 2; ++ds) {
                bf16x8 afr = *reinterpret_cast<const bf16x8*>(&AL[(w * 16 + l15) * 72 + ds * 32 + lgp * 8]);
                #pragma unroll
                for (int ot = 0; ot < 4; ++ot) {
                    bf16x8 bfr = *reinterpret_cast<const bf16x8*>(&BL[(ot * 16 + l15) * 72 + ds * 32 + lgp * 8]);
                    acc[ot] = __builtin_amdgcn_mfma_f32_16x16x32_bf16(afr, bfr, acc[ot], 0, 0, 0);
                }
            }
        }
    }
    const int j0 = jc * 64, o0 = oc * 64;
    float* dst = part + (size_t)slot * 512 * 256;
    #pragma unroll
    for (int ot = 0; ot < 4; ++ot)
        #pragma unroll
        for (int i = 0; i < 4; ++i) {
            int rr = j0 + w * 16 + lgp * 4 + i;
            int o = o0 + ot * 16 + l15;
            dst[rr * 256 + o] = acc[ot][i];
        }
}

// ---------- K4a: combine partials + biases -> ypre, per-chunk BN stats ----------
__global__ void k4a_comb(const float* __restrict__ part,
                         const float* __restrict__ pb2, const float* __restrict__ pb3,
                         float* __restrict__ ypre,
                         float* __restrict__ psum, float* __restrict__ psq)
{
    int g = blockIdx.x, o = threadIdx.x;
    float bsum = pb2[o] + pb3[o];
    float s = 0.f, q = 0.f;
    for (int r = g * 8; r < g * 8 + 8; ++r) {
        size_t idx = (size_t)r * 256 + o;
        float v = part[idx] + part[131072 + idx] + part[2 * 131072 + idx]
                + part[3 * 131072 + idx] + part[4 * 131072 + idx] + bsum;
        ypre[idx] = v;
        s += v; q += v * v;
    }
    psum[g * 256 + o] = s;
    psq[g * 256 + o] = q;
}

// ---------- K4c: fold 64-chunk stats -> mu, inv ----------
__global__ void k4c_stats(const float* __restrict__ psum, const float* __restrict__ psq,
                          float* __restrict__ mu, float* __restrict__ inv) {
    int o = threadIdx.x;
    float s = 0.f, q = 0.f;
    for (int g = 0; g < 64; ++g) {
        s += psum[g * 256 + o];
        q += psq[g * 256 + o];
    }
    float m = s * (1.f / 512.f);
    float var = q * (1.f / 512.f) - m * m;
    mu[o] = m;
    inv[o] = rsqrtf(var + 1e-5f);
}

// ---------- K4b: normalize + affine + SELU -> FP32 output ----------
__global__ void k4b_norm(const float* __restrict__ ypre,
                         const float* __restrict__ mu, const float* __restrict__ inv,
                         const float* __restrict__ gamma, const float* __restrict__ beta,
                         float* __restrict__ out) {
    int r = blockIdx.x, o = threadIdx.x;
    float v = (ypre[r * 256 + o] - mu[o]) * inv[o] * gamma[o] + beta[o];
    const float SC = 1.0507009873554805f, AL = 1.6732632423543772f;
    float ov = v > 0.f ? SC * v : SC * AL * (__expf(v) - 1.f);
    out[r * 256 + o] = ov;
}

extern "C" void kernel_launch(void* const* d_in, const int* in_sizes, int n_in,
                              void* d_out, int out_size, void* d_ws, size_t ws_size,
                              hipStream_t stream) {
    const float* x    = (const float*)d_in[0];
    const int* bnd    = (const int*)d_in[1];
    const float* Wap  = (const float*)d_in[2];
    const float* bap  = (const float*)d_in[3];
    const float* aw   = (const float*)d_in[4];
    const float* W2   = (const float*)d_in[5];
    const float* pb2  = (const float*)d_in[6];
    const float* W3   = (const float*)d_in[7];
    const float* pb3  = (const float*)d_in[8];
    const float* gamma = (const float*)d_in[9];
    const float* beta  = (const float*)d_in[10];
    float* out = (float*)d_out;
    (void)in_sizes; (void)n_in; (void)out_size; (void)ws_size;

    char* ws = (char*)d_ws;
    u16* Xbf   = (u16*)ws;  ws += (size_t)B_ * T_ * D_ * 2;
    u16* XT    = (u16*)ws;  ws += (size_t)B_ * D_ * T_ * 2;
    u16* p_ws  = (u16*)ws;  ws += (size_t)B_ * H_ * T_ * T_ * 2;
    u16* x1    = (u16*)ws;  ws += (size_t)B_ * T_ * D_ * H_ * 2;
    float* part = (float*)ws; ws += (size_t)5 * 512 * 256 * 4;
    float* ypre = (float*)ws; ws += (size_t)B_ * T_ * O_ * 4;
    float* psum = (float*)ws; ws += (size_t)64 * O_ * 4;
    float* psq  = (float*)ws; ws += (size_t)64 * O_ * 4;
    float* muv  = (float*)ws; ws += (size_t)O_ * 4;
    float* invv = (float*)ws; ws += (size_t)O_ * 4;

    k0_convert<<<64, 256, 0, stream>>>(x, Xbf, XT);
    k1_att<<<512, 256, 0, stream>>>(Xbf, x, bnd, Wap, bap, aw, p_ws);
    k2_agg<<<128, 256, 0, stream>>>(p_ws, XT, x1);
    k3_mm<<<160, 256, 0, stream>>>(x1, x, W2, W3, part);
    k4a_comb<<<64, 256, 0, stream>>>(part, pb2, pb3, ypre, psum, psq);
    k4c_stats<<<1, 256, 0, stream>>>(psum, psq, muv, invv);
    k4b_norm<<<512, 256, 0, stream>>>(ypre, muv, invv, gamma, beta, out);
}

// Round 10
// 117.917 us; speedup vs baseline: 13.0359x; 1.0026x over previous
//
#include <hip/hip_runtime.h>
#include <hip/hip_bf16.h>

// Problem: B=2, T=256, IN_DIM=512, OUT_DIM=256, H=8, TEMP=1, BN_EPS=1e-5
// Device dtypes: inputs fp32 (boundary int32), OUTPUT fp32.
// ROUND 10: k1 split over oc (grid 512 -> 2048, serial path /4) + k1b reduce
// with mask+softmax. LDS per block ~46KB -> 3 blocks/CU.
#define B_ 2
#define T_ 256
#define D_ 512
#define O_ 256
#define H_ 8

typedef __attribute__((ext_vector_type(4))) float f32x4;
typedef __attribute__((ext_vector_type(8))) short bf16x8;
typedef unsigned short u16;
typedef unsigned int u32;

__device__ __forceinline__ float b2f(u16 u) {
    u32 t = ((u32)u) << 16;
    return __builtin_bit_cast(float, t);
}
__device__ __forceinline__ u16 f2b(float f) {
    u32 u = __builtin_bit_cast(u32, f);
    u32 r = (u + 0x7FFFu + ((u >> 16) & 1u)) >> 16;  // RNE
    return (u16)r;
}
__device__ __forceinline__ float fast_tanh(float x) {
    float ax = fabsf(x);
    float e = __expf(-2.f * ax);
    float r = (1.f - e) / (1.f + e);
    return x < 0.f ? -r : r;
}
__device__ __forceinline__ uint4 ld8f2b(const float* __restrict__ p) {
    f32x4 a = *reinterpret_cast<const f32x4*>(p);
    f32x4 b = *reinterpret_cast<const f32x4*>(p + 4);
    u16 t[8] = {f2b(a[0]), f2b(a[1]), f2b(a[2]), f2b(a[3]),
                f2b(b[0]), f2b(b[1]), f2b(b[2]), f2b(b[3])};
    return *reinterpret_cast<uint4*>(t);
}
__device__ __forceinline__ void gload16(const void* g, void* l) {
    __builtin_amdgcn_global_load_lds(
        (const __attribute__((address_space(1))) unsigned int*)g,
        (__attribute__((address_space(3))) unsigned int*)l, 16, 0, 0);
}

// ---------- K0: Xbf[b][k][d] = bf16(x), XT[b][d][k] = bf16(x[b][k][d]) ----------
__global__ void k0_convert(const float* __restrict__ x,
                           u16* __restrict__ Xbf, u16* __restrict__ XT) {
    int idx = blockIdx.x;
    int dt = idx & 7, kt = (idx >> 3) & 3, b = idx >> 5;
    __shared__ u16 tile[64][65];
    int tid = threadIdx.x;
    for (int c = tid; c < 4096; c += 256) {
        int r = c >> 6, col = c & 63;
        float v = x[(b * 256 + kt * 64 + r) * 512 + dt * 64 + col];
        u16 hv = f2b(v);
        tile[r][col] = hv;
        Xbf[(b * 256 + kt * 64 + r) * 512 + dt * 64 + col] = hv;
    }
    __syncthreads();
    for (int c = tid; c < 4096; c += 256) {
        int rr = c >> 6, cc = c & 63;
        XT[(b * 512 + dt * 64 + rr) * 256 + kt * 64 + cc] = tile[cc][rr];
    }
}

// ---------- K1a: per-(b,j,oc) pair-GEMM + tanh + partial att -> attpart ----------
// grid 2048: bx = ((b*256 + j)*4 + oc). attpart[b][j][oc][k][h] fp32.
__launch_bounds__(256, 3)
__global__ void k1a_att(const u16* __restrict__ Xbf, const float* __restrict__ xf,
                        const float* __restrict__ Wap, const float* __restrict__ bap,
                        const float* __restrict__ aw, float* __restrict__ attpart)
{
    const int oc = blockIdx.x & 3;
    const int j = (blockIdx.x >> 2) & 255;
    const int b = blockIdx.x >> 10;
    const int tid = threadIdx.x;
    const int w = tid >> 6;
    const int l = tid & 63;
    const int l15 = l & 15;
    const int lgp = l >> 4;

    __shared__ __align__(16) u16 XL[256 * 64];   // 32 KB swizzled DMA dest; reused as a_lds
    __shared__ __align__(16) u16 WL[64 * 72];    // Wj tile (o_local x 64d), pad 72
    __shared__ __align__(16) u16 awT[16 * 72];   // aw chunk [h][o_local], rows 8..15 zero
    __shared__ float xj[512];

    const u16* xb = Xbf + b * (T_ * D_);
    const float* xjp = xf + (b * T_ + j) * D_;
    for (int i = tid; i < D_; i += 256) xj[i] = xjp[i];
    for (int i = tid; i < 16 * 72; i += 256) awT[i] = 0;
    __syncthreads();
    for (int i = tid; i < 64 * 8; i += 256) {
        int ol = i >> 3, h = i & 7;
        awT[h * 72 + ol] = f2b(aw[(oc * 64 + ol) * 8 + h]);
    }

    const int srow_off = (l >> 3);
    const int scol = ((l & 7) ^ ((l >> 3) & 7)) * 8;

    f32x4 acc[4][4] = {};              // C'[o,k] tiles [ot][kt]
    for (int d0 = 0; d0 < D_; d0 += 64) {
        __syncthreads();
        #pragma unroll
        for (int i = 0; i < 8; ++i) {
            int row = i * 32 + w * 8 + srow_off;
            gload16(xb + row * 512 + d0 + scol, &XL[i * 2048 + w * 512]);
        }
        #pragma unroll
        for (int c = 0; c < 2; ++c) {
            int cc = tid + c * 256;
            int r = cc >> 3, s = cc & 7;
            const float* wp = Wap + (oc * 64 + r) * 512 + d0 + s * 8;
            f32x4 va = *reinterpret_cast<const f32x4*>(wp);
            f32x4 vb = *reinterpret_cast<const f32x4*>(wp + 4);
            const float* xq = &xj[d0 + s * 8];
            u16 tmp[8];
            #pragma unroll
            for (int e = 0; e < 4; ++e) tmp[e] = f2b(va[e] * xq[e]);
            #pragma unroll
            for (int e = 0; e < 4; ++e) tmp[4 + e] = f2b(vb[e] * xq[4 + e]);
            *reinterpret_cast<uint4*>(&WL[r * 72 + s * 8]) =
                *reinterpret_cast<const uint4*>(tmp);
        }
        __syncthreads();
        #pragma unroll
        for (int ds = 0; ds < 2; ++ds) {
            bf16x8 wfr[4];
            #pragma unroll
            for (int ot = 0; ot < 4; ++ot)
                wfr[ot] = *reinterpret_cast<const bf16x8*>(&WL[(ot * 16 + l15) * 72 + ds * 32 + lgp * 8]);
            #pragma unroll
            for (int kt = 0; kt < 4; ++kt) {
                int row = w * 64 + kt * 16 + l15;
                int c16 = ((ds * 4 + lgp) ^ (l15 & 7)) * 8;
                bf16x8 xfr = *reinterpret_cast<const bf16x8*>(&XL[row * 64 + c16]);
                #pragma unroll
                for (int ot = 0; ot < 4; ++ot)
                    acc[ot][kt] = __builtin_amdgcn_mfma_f32_16x16x32_bf16(wfr[ot], xfr, acc[ot][kt], 0, 0, 0);
            }
        }
    }
    // tanh(s + bias) -> a_lds (aliases XL, same swizzle); own k-strip only
    u16* a_lds = XL;
    #pragma unroll
    for (int ot = 0; ot < 4; ++ot) {
        f32x4 bv = *reinterpret_cast<const f32x4*>(bap + oc * 64 + ot * 16 + lgp * 4);
        #pragma unroll
        for (int kt = 0; kt < 4; ++kt) {
            int k = w * 64 + kt * 16 + l15;
            u16 t0 = f2b(fast_tanh(acc[ot][kt][0] + bv[0]));
            u16 t1 = f2b(fast_tanh(acc[ot][kt][1] + bv[1]));
            u16 t2 = f2b(fast_tanh(acc[ot][kt][2] + bv[2]));
            u16 t3 = f2b(fast_tanh(acc[ot][kt][3] + bv[3]));
            uint2 pk;
            pk.x = (u32)t0 | ((u32)t1 << 16);
            pk.y = (u32)t2 | ((u32)t3 << 16);
            int c16 = (ot * 2 + (lgp >> 1)) ^ (l15 & 7);
            *reinterpret_cast<uint2*>(&a_lds[k * 64 + c16 * 8 + (lgp & 1) * 4]) = pk;
        }
    }
    // partial att[k,h] = a[k, o-chunk] · awT[h, o-chunk]^T
    f32x4 attacc[4] = {};
    #pragma unroll
    for (int ds = 0; ds < 2; ++ds) {
        bf16x8 bw = *reinterpret_cast<const bf16x8*>(&awT[l15 * 72 + ds * 32 + lgp * 8]);
        #pragma unroll
        for (int kt = 0; kt < 4; ++kt) {
            int row = w * 64 + kt * 16 + l15;
            int c16 = ((ds * 4 + lgp) ^ (l15 & 7)) * 8;
            bf16x8 af = *reinterpret_cast<const bf16x8*>(&a_lds[row * 64 + c16]);
            attacc[kt] = __builtin_amdgcn_mfma_f32_16x16x32_bf16(af, bw, attacc[kt], 0, 0, 0);
        }
    }
    // write partial: attpart[((b*256+j)*4 + oc)][k][h]
    float* dst = attpart + ((size_t)blockIdx.x) * 256 * 8;
    #pragma unroll
    for (int kt = 0; kt < 4; ++kt) {
        if (l15 < 8) {
            #pragma unroll
            for (int i = 0; i < 4; ++i) {
                int k = w * 64 + kt * 16 + lgp * 4 + i;
                dst[k * 8 + l15] = attacc[kt][i];
            }
        }
    }
}

// ---------- K1b: sum 4 oc-parts + mask + softmax -> p_ws ----------
__global__ void k1b_sm(const float* __restrict__ attpart, const int* __restrict__ bnd,
                       u16* __restrict__ p_ws)
{
    const int b = blockIdx.x >> 8;
    const int j = blockIdx.x & 255;
    const int tid = threadIdx.x;

    __shared__ float attL[256 * 9];
    __shared__ float maskv[256];
    __shared__ int scanv[256];

    scanv[tid] = bnd[b * T_ + tid];
    __syncthreads();
    for (int off = 1; off < 256; off <<= 1) {
        int v = (tid >= off) ? scanv[tid - off] : 0;
        __syncthreads();
        scanv[tid] += v;
        __syncthreads();
    }
    {
        int k = tid;
        float m;
        if (k == j) m = 1.f;
        else if (k > j) m = ((scanv[k] - (j ? scanv[j - 1] : 0)) == 0) ? 1.f : 0.f;
        else m = ((scanv[j] - (k ? scanv[k - 1] : 0)) == 0) ? 1.f : 0.f;
        maskv[k] = m;
    }
    // sum parts: thread k handles its row (8 h values, 4 oc parts)
    {
        const float* base = attpart + ((size_t)(b * 256 + j) * 4) * 256 * 8 + tid * 8;
        f32x4 s0 = *reinterpret_cast<const f32x4*>(base);
        f32x4 s1 = *reinterpret_cast<const f32x4*>(base + 4);
        #pragma unroll
        for (int oc = 1; oc < 4; ++oc) {
            s0 += *reinterpret_cast<const f32x4*>(base + (size_t)oc * 2048);
            s1 += *reinterpret_cast<const f32x4*>(base + (size_t)oc * 2048 + 4);
        }
        #pragma unroll
        for (int e = 0; e < 4; ++e) attL[tid * 9 + e] = s0[e];
        #pragma unroll
        for (int e = 0; e < 4; ++e) attL[tid * 9 + 4 + e] = s1[e];
    }
    __syncthreads();

    {
        int h = tid >> 5, c = tid & 31;
        float lgv[8];
        float mx = -3.4e38f;
        #pragma unroll
        for (int kk = 0; kk < 8; ++kk) {
            int k = c + kk * 32;
            float v = attL[k * 9 + h] * maskv[k];
            lgv[kk] = v;
            mx = fmaxf(mx, v);
        }
        #pragma unroll
        for (int off = 1; off < 32; off <<= 1)
            mx = fmaxf(mx, __shfl_xor(mx, off, 32));
        float sum = 0.f;
        #pragma unroll
        for (int kk = 0; kk < 8; ++kk) {
            lgv[kk] = __expf(lgv[kk] - mx);
            sum += lgv[kk];
        }
        #pragma unroll
        for (int off = 1; off < 32; off <<= 1)
            sum += __shfl_xor(sum, off, 32);
        float inv = 1.f / sum;
        u16* dst = p_ws + (((b * 8 + h) * 256 + j) * 256);
        #pragma unroll
        for (int kk = 0; kk < 8; ++kk)
            dst[c + kk * 32] = f2b(lgv[kk] * inv);
    }
}

// ---------- K2: x1[b][j][d*8+h] = sum_k p[b,h,j,k] * x[b,k,d] (MFMA) ----------
__launch_bounds__(256, 2)
__global__ void k2_agg(const u16* __restrict__ p_ws, const u16* __restrict__ XT,
                       u16* __restrict__ x1)
{
    const int bh = blockIdx.x >> 3;
    const int dc = blockIdx.x & 7;
    const int b = bh >> 3;
    const int h = bh & 7;
    const int tid = threadIdx.x;
    const int w = tid >> 6, l = tid & 63, l15 = l & 15, lgp = l >> 4;

    __shared__ __align__(16) u16 AL[256 * 72];
    __shared__ __align__(16) u16 BL[64 * 72];

    const u16* A = p_ws + bh * (256 * 256);
    const u16* Bx = XT + (b * 512 + dc * 64) * 256;

    f32x4 acc[4][4] = {};
    for (int k0 = 0; k0 < 256; k0 += 64) {
        __syncthreads();
        #pragma unroll
        for (int c = 0; c < 8; ++c) {
            int cc = tid + c * 256;
            int r = cc >> 3, s = cc & 7;
            *reinterpret_cast<uint4*>(&AL[r * 72 + s * 8]) =
                *reinterpret_cast<const uint4*>(A + r * 256 + k0 + s * 8);
        }
        #pragma unroll
        for (int c = 0; c < 2; ++c) {
            int cc = tid + c * 256;
            int r = cc >> 3, s = cc & 7;
            *reinterpret_cast<uint4*>(&BL[r * 72 + s * 8]) =
                *reinterpret_cast<const uint4*>(Bx + r * 256 + k0 + s * 8);
        }
        __syncthreads();
        #pragma unroll
        for (int ds = 0; ds < 2; ++ds) {
            bf16x8 bfr[4];
            #pragma unroll
            for (int ot = 0; ot < 4; ++ot)
                bfr[ot] = *reinterpret_cast<const bf16x8*>(&BL[(ot * 16 + l15) * 72 + ds * 32 + lgp * 8]);
            #pragma unroll
            for (int kt = 0; kt < 4; ++kt) {
                bf16x8 afr = *reinterpret_cast<const bf16x8*>(&AL[(w * 64 + kt * 16 + l15) * 72 + ds * 32 + lgp * 8]);
                #pragma unroll
                for (int ot = 0; ot < 4; ++ot)
                    acc[kt][ot] = __builtin_amdgcn_mfma_f32_16x16x32_bf16(afr, bfr[ot], acc[kt][ot], 0, 0, 0);
            }
        }
    }
    #pragma unroll
    for (int kt = 0; kt < 4; ++kt)
        #pragma unroll
        for (int ot = 0; ot < 4; ++ot)
            #pragma unroll
            for (int i = 0; i < 4; ++i) {
                int jj = w * 64 + kt * 16 + lgp * 4 + i;
                int d = dc * 64 + ot * 16 + l15;
                x1[(b * 256 + jj) * 4096 + d * 8 + h] = f2b(acc[kt][ot][i]);
            }
}

// ---------- K3: split-K projections -> 5 partial buffers ----------
__launch_bounds__(256, 4)
__global__ void k3_mm(const u16* __restrict__ x1, const float* __restrict__ x,
                      const float* __restrict__ W2, const float* __restrict__ W3,
                      float* __restrict__ part)
{
    const int gid = blockIdx.x;
    const int tid = threadIdx.x;
    const int w = tid >> 6, l = tid & 63, l15 = l & 15, lgp = l >> 4;

    __shared__ __align__(16) u16 AL[64 * 72];
    __shared__ __align__(16) u16 BL[64 * 72];

    f32x4 acc[4] = {};
    int jc, oc, slot;
    if (gid < 128) {
        int kc = gid & 3;
        oc = (gid >> 2) & 3;
        jc = gid >> 4;
        slot = kc;
        const int j0 = jc * 64, o0 = oc * 64;
        const int tbeg = kc * 1024, tend = tbeg + 1024;
        for (int t0 = tbeg; t0 < tend; t0 += 64) {
            __syncthreads();
            #pragma unroll
            for (int c = 0; c < 2; ++c) {
                int cc = tid + c * 256;
                int r = cc >> 3, s = cc & 7;
                *reinterpret_cast<uint4*>(&AL[r * 72 + s * 8]) =
                    *reinterpret_cast<const uint4*>(x1 + (size_t)(j0 + r) * 4096 + t0 + s * 8);
                *reinterpret_cast<uint4*>(&BL[r * 72 + s * 8]) =
                    ld8f2b(W2 + (size_t)(o0 + r) * 4096 + t0 + s * 8);
            }
            __syncthreads();
            #pragma unroll
            for (int ds = 0; ds < 2; ++ds) {
                bf16x8 afr = *reinterpret_cast<const bf16x8*>(&AL[(w * 16 + l15) * 72 + ds * 32 + lgp * 8]);
                #pragma unroll
                for (int ot = 0; ot < 4; ++ot) {
                    bf16x8 bfr = *reinterpret_cast<const bf16x8*>(&BL[(ot * 16 + l15) * 72 + ds * 32 + lgp * 8]);
                    acc[ot] = __builtin_amdgcn_mfma_f32_16x16x32_bf16(afr, bfr, acc[ot], 0, 0, 0);
                }
            }
        }
    } else {
        int g2 = gid - 128;
        oc = g2 & 3;
        jc = g2 >> 2;
        slot = 4;
        const int j0 = jc * 64, o0 = oc * 64;
        for (int t0 = 0; t0 < 512; t0 += 64) {
            __syncthreads();
            #pragma unroll
            for (int c = 0; c < 2; ++c) {
                int cc = tid + c * 256;
                int r = cc >> 3, s = cc & 7;
                *reinterpret_cast<uint4*>(&AL[r * 72 + s * 8]) =
                    ld8f2b(x + (size_t)(j0 + r) * 512 + t0 + s * 8);
                *reinterpret_cast<uint4*>(&BL[r * 72 + s * 8]) =
                    ld8f2b(W3 + (size_t)(o0 + r) * 512 + t0 + s * 8);
            }
            __syncthreads();
            #pragma unroll
            for (int ds = 0; ds < 2; ++ds) {
                bf16x8 afr = *reinterpret_cast<const bf16x8*>(&AL[(w * 16 + l15) * 72 + ds * 32 + lgp * 8]);
                #pragma unroll
                for (int ot = 0; ot < 4; ++ot) {
                    bf16x8 bfr = *reinterpret_cast<const bf16x8*>(&BL[(ot * 16 + l15) * 72 + ds * 32 + lgp * 8]);
                    acc[ot] = __builtin_amdgcn_mfma_f32_16x16x32_bf16(afr, bfr, acc[ot], 0, 0, 0);
                }
            }
        }
    }
    const int j0 = jc * 64, o0 = oc * 64;
    float* dst = part + (size_t)slot * 512 * 256;
    #pragma unroll
    for (int ot = 0; ot < 4; ++ot)
        #pragma unroll
        for (int i = 0; i < 4; ++i) {
            int rr = j0 + w * 16 + lgp * 4 + i;
            int o = o0 + ot * 16 + l15;
            dst[rr * 256 + o] = acc[ot][i];
        }
}

// ---------- K4a: combine partials + biases -> ypre, per-chunk BN stats ----------
__global__ void k4a_comb(const float* __restrict__ part,
                         const float* __restrict__ pb2, const float* __restrict__ pb3,
                         float* __restrict__ ypre,
                         float* __restrict__ psum, float* __restrict__ psq)
{
    int g = blockIdx.x, o = threadIdx.x;
    float bsum = pb2[o] + pb3[o];
    float s = 0.f, q = 0.f;
    for (int r = g * 8; r < g * 8 + 8; ++r) {
        size_t idx = (size_t)r * 256 + o;
        float v = part[idx] + part[131072 + idx] + part[2 * 131072 + idx]
                + part[3 * 131072 + idx] + part[4 * 131072 + idx] + bsum;
        ypre[idx] = v;
        s += v; q += v * v;
    }
    psum[g * 256 + o] = s;
    psq[g * 256 + o] = q;
}

// ---------- K4c: fold 64-chunk stats -> mu, inv ----------
__global__ void k4c_stats(const float* __restrict__ psum, const float* __restrict__ psq,
                          float* __restrict__ mu, float* __restrict__ inv) {
    int o = threadIdx.x;
    float s = 0.f, q = 0.f;
    for (int g = 0; g < 64; ++g) {
        s += psum[g * 256 + o];
        q += psq[g * 256 + o];
    }
    float m = s * (1.f / 512.f);
    float var = q * (1.f / 512.f) - m * m;
    mu[o] = m;
    inv[o] = rsqrtf(var + 1e-5f);
}

// ---------- K4b: normalize + affine + SELU -> FP32 output ----------
__global__ void k4b_norm(const float* __restrict__ ypre,
                         const float* __restrict__ mu, const float* __restrict__ inv,
                         const float* __restrict__ gamma, const float* __restrict__ beta,
                         float* __restrict__ out) {
    int r = blockIdx.x, o = threadIdx.x;
    float v = (ypre[r * 256 + o] - mu[o]) * inv[o] * gamma[o] + beta[o];
    const float SC = 1.0507009873554805f, AL = 1.6732632423543772f;
    float ov = v > 0.f ? SC * v : SC * AL * (__expf(v) - 1.f);
    out[r * 256 + o] = ov;
}

extern "C" void kernel_launch(void* const* d_in, const int* in_sizes, int n_in,
                              void* d_out, int out_size, void* d_ws, size_t ws_size,
                              hipStream_t stream) {
    const float* x    = (const float*)d_in[0];
    const int* bnd    = (const int*)d_in[1];
    const float* Wap  = (const float*)d_in[2];
    const float* bap  = (const float*)d_in[3];
    const float* aw   = (const float*)d_in[4];
    const float* W2   = (const float*)d_in[5];
    const float* pb2  = (const float*)d_in[6];
    const float* W3   = (const float*)d_in[7];
    const float* pb3  = (const float*)d_in[8];
    const float* gamma = (const float*)d_in[9];
    const float* beta  = (const float*)d_in[10];
    float* out = (float*)d_out;
    (void)in_sizes; (void)n_in; (void)out_size; (void)ws_size;

    char* ws = (char*)d_ws;
    u16* Xbf   = (u16*)ws;  ws += (size_t)B_ * T_ * D_ * 2;         // 512 KB
    u16* XT    = (u16*)ws;  ws += (size_t)B_ * D_ * T_ * 2;         // 512 KB
    u16* p_ws  = (u16*)ws;  ws += (size_t)B_ * H_ * T_ * T_ * 2;    // 2 MB
    u16* x1    = (u16*)ws;  ws += (size_t)B_ * T_ * D_ * H_ * 2;    // 4 MB
    float* part = (float*)ws; ws += (size_t)5 * 512 * 256 * 4;      // 2.6 MB
    float* ypre = (float*)ws; ws += (size_t)B_ * T_ * O_ * 4;       // 512 KB
    float* psum = (float*)ws; ws += (size_t)64 * O_ * 4;
    float* psq  = (float*)ws; ws += (size_t)64 * O_ * 4;
    float* muv  = (float*)ws; ws += (size_t)O_ * 4;
    float* invv = (float*)ws; ws += (size_t)O_ * 4;
    float* attpart = (float*)ws; ws += (size_t)2048 * 256 * 8 * 4;  // 16.8 MB

    k0_convert<<<64, 256, 0, stream>>>(x, Xbf, XT);
    k1a_att<<<2048, 256, 0, stream>>>(Xbf, x, Wap, bap, aw, attpart);
    k1b_sm<<<512, 256, 0, stream>>>(attpart, bnd, p_ws);
    k2_agg<<<128, 256, 0, stream>>>(p_ws, XT, x1);
    k3_mm<<<160, 256, 0, stream>>>(x1, x, W2, W3, part);
    k4a_comb<<<64, 256, 0, stream>>>(part, pb2, pb3, ypre, psum, psq);
    k4c_stats<<<1, 256, 0, stream>>>(psum, psq, muv, invv);
    k4b_norm<<<512, 256, 0, stream>>>(ypre, muv, invv, gamma, beta, out);
}

// Round 11
// 110.659 us; speedup vs baseline: 13.8909x; 1.0656x over previous
//
#include <hip/hip_runtime.h>
#include <hip/hip_bf16.h>

// Problem: B=2, T=256, IN_DIM=512, OUT_DIM=256, H=8, TEMP=1, BN_EPS=1e-5
// Device dtypes: inputs fp32 (boundary int32), OUTPUT fp32.
// ROUND 11: exploit (j,k) symmetry of logits — each (b,j,oc) block computes
// only k-strips >= jt (wave w active iff w>=jt) and mirror-writes att[k][j]
// for strips w>jt. Aggregate main-loop work -> 62.5%.
#define B_ 2
#define T_ 256
#define D_ 512
#define O_ 256
#define H_ 8

typedef __attribute__((ext_vector_type(4))) float f32x4;
typedef __attribute__((ext_vector_type(8))) short bf16x8;
typedef unsigned short u16;
typedef unsigned int u32;

__device__ __forceinline__ float b2f(u16 u) {
    u32 t = ((u32)u) << 16;
    return __builtin_bit_cast(float, t);
}
__device__ __forceinline__ u16 f2b(float f) {
    u32 u = __builtin_bit_cast(u32, f);
    u32 r = (u + 0x7FFFu + ((u >> 16) & 1u)) >> 16;  // RNE
    return (u16)r;
}
__device__ __forceinline__ float fast_tanh(float x) {
    float ax = fabsf(x);
    float e = __expf(-2.f * ax);
    float r = (1.f - e) / (1.f + e);
    return x < 0.f ? -r : r;
}
__device__ __forceinline__ uint4 ld8f2b(const float* __restrict__ p) {
    f32x4 a = *reinterpret_cast<const f32x4*>(p);
    f32x4 b = *reinterpret_cast<const f32x4*>(p + 4);
    u16 t[8] = {f2b(a[0]), f2b(a[1]), f2b(a[2]), f2b(a[3]),
                f2b(b[0]), f2b(b[1]), f2b(b[2]), f2b(b[3])};
    return *reinterpret_cast<uint4*>(t);
}
__device__ __forceinline__ void gload16(const void* g, void* l) {
    __builtin_amdgcn_global_load_lds(
        (const __attribute__((address_space(1))) unsigned int*)g,
        (__attribute__((address_space(3))) unsigned int*)l, 16, 0, 0);
}

// ---------- K0: Xbf[b][k][d] = bf16(x), XT[b][d][k] = bf16(x[b][k][d]) ----------
__global__ void k0_convert(const float* __restrict__ x,
                           u16* __restrict__ Xbf, u16* __restrict__ XT) {
    int idx = blockIdx.x;
    int dt = idx & 7, kt = (idx >> 3) & 3, b = idx >> 5;
    __shared__ u16 tile[64][65];
    int tid = threadIdx.x;
    for (int c = tid; c < 4096; c += 256) {
        int r = c >> 6, col = c & 63;
        float v = x[(b * 256 + kt * 64 + r) * 512 + dt * 64 + col];
        u16 hv = f2b(v);
        tile[r][col] = hv;
        Xbf[(b * 256 + kt * 64 + r) * 512 + dt * 64 + col] = hv;
    }
    __syncthreads();
    for (int c = tid; c < 4096; c += 256) {
        int rr = c >> 6, cc = c & 63;
        XT[(b * 512 + dt * 64 + rr) * 256 + kt * 64 + cc] = tile[cc][rr];
    }
}

// ---------- K1a: per-(b,j,oc) pair-GEMM + tanh + partial att, symmetric-half ----------
// grid 2048: bx = ((b*256 + j)*4 + oc). attpart[(b*256+j)*4+oc][k][h] fp32.
// Wave w computes k-strip [w*64,(w+1)*64) iff w >= jt (jt=j>>6); strips w>jt
// also mirror-write att[k][j] into the k-rows' buffers.
__launch_bounds__(256, 3)
__global__ void k1a_att(const u16* __restrict__ Xbf, const float* __restrict__ xf,
                        const float* __restrict__ Wap, const float* __restrict__ bap,
                        const float* __restrict__ aw, float* __restrict__ attpart)
{
    const int oc = blockIdx.x & 3;
    const int j = (blockIdx.x >> 2) & 255;
    const int b = blockIdx.x >> 10;
    const int jt = j >> 6;
    const int tid = threadIdx.x;
    const int w = tid >> 6;
    const int l = tid & 63;
    const int l15 = l & 15;
    const int lgp = l >> 4;
    const bool act = (w >= jt);

    __shared__ __align__(16) u16 XL[256 * 64];   // swizzled DMA dest; reused as a_lds
    __shared__ __align__(16) u16 WL[64 * 72];    // Wj tile (o_local x 64d), pad 72
    __shared__ __align__(16) u16 awT[16 * 72];   // aw chunk [h][o_local], rows 8..15 zero
    __shared__ float xj[512];

    const u16* xb = Xbf + b * (T_ * D_);
    const float* xjp = xf + (b * T_ + j) * D_;
    for (int i = tid; i < D_; i += 256) xj[i] = xjp[i];
    for (int i = tid; i < 16 * 72; i += 256) awT[i] = 0;
    __syncthreads();
    for (int i = tid; i < 64 * 8; i += 256) {
        int ol = i >> 3, h = i & 7;
        awT[h * 72 + ol] = f2b(aw[(oc * 64 + ol) * 8 + h]);
    }

    const int srow_off = (l >> 3);
    const int scol = ((l & 7) ^ ((l >> 3) & 7)) * 8;
    const int i0 = jt * 2;   // first staging issue (rows >= jt*64)

    f32x4 acc[4][4] = {};              // C'[o,k] tiles [ot][kt] for this wave's strip
    for (int d0 = 0; d0 < D_; d0 += 64) {
        __syncthreads();
        #pragma unroll
        for (int i = 0; i < 8; ++i) {
            if (i >= i0) {
                int row = i * 32 + w * 8 + srow_off;
                gload16(xb + row * 512 + d0 + scol, &XL[i * 2048 + w * 512]);
            }
        }
        #pragma unroll
        for (int c = 0; c < 2; ++c) {
            int cc = tid + c * 256;
            int r = cc >> 3, s = cc & 7;
            const float* wp = Wap + (oc * 64 + r) * 512 + d0 + s * 8;
            f32x4 va = *reinterpret_cast<const f32x4*>(wp);
            f32x4 vb = *reinterpret_cast<const f32x4*>(wp + 4);
            const float* xq = &xj[d0 + s * 8];
            u16 tmp[8];
            #pragma unroll
            for (int e = 0; e < 4; ++e) tmp[e] = f2b(va[e] * xq[e]);
            #pragma unroll
            for (int e = 0; e < 4; ++e) tmp[4 + e] = f2b(vb[e] * xq[4 + e]);
            *reinterpret_cast<uint4*>(&WL[r * 72 + s * 8]) =
                *reinterpret_cast<const uint4*>(tmp);
        }
        __syncthreads();
        if (act) {
            #pragma unroll
            for (int ds = 0; ds < 2; ++ds) {
                bf16x8 wfr[4];
                #pragma unroll
                for (int ot = 0; ot < 4; ++ot)
                    wfr[ot] = *reinterpret_cast<const bf16x8*>(&WL[(ot * 16 + l15) * 72 + ds * 32 + lgp * 8]);
                #pragma unroll
                for (int kt = 0; kt < 4; ++kt) {
                    int row = w * 64 + kt * 16 + l15;
                    int c16 = ((ds * 4 + lgp) ^ (l15 & 7)) * 8;
                    bf16x8 xfr = *reinterpret_cast<const bf16x8*>(&XL[row * 64 + c16]);
                    #pragma unroll
                    for (int ot = 0; ot < 4; ++ot)
                        acc[ot][kt] = __builtin_amdgcn_mfma_f32_16x16x32_bf16(wfr[ot], xfr, acc[ot][kt], 0, 0, 0);
                }
            }
        }
    }
    // tanh(s + bias) -> a_lds (aliases XL, same swizzle); own k-strip only
    u16* a_lds = XL;
    if (act) {
        #pragma unroll
        for (int ot = 0; ot < 4; ++ot) {
            f32x4 bv = *reinterpret_cast<const f32x4*>(bap + oc * 64 + ot * 16 + lgp * 4);
            #pragma unroll
            for (int kt = 0; kt < 4; ++kt) {
                int k = w * 64 + kt * 16 + l15;
                u16 t0 = f2b(fast_tanh(acc[ot][kt][0] + bv[0]));
                u16 t1 = f2b(fast_tanh(acc[ot][kt][1] + bv[1]));
                u16 t2 = f2b(fast_tanh(acc[ot][kt][2] + bv[2]));
                u16 t3 = f2b(fast_tanh(acc[ot][kt][3] + bv[3]));
                uint2 pk;
                pk.x = (u32)t0 | ((u32)t1 << 16);
                pk.y = (u32)t2 | ((u32)t3 << 16);
                int c16 = (ot * 2 + (lgp >> 1)) ^ (l15 & 7);
                *reinterpret_cast<uint2*>(&a_lds[k * 64 + c16 * 8 + (lgp & 1) * 4]) = pk;
            }
        }
    }
    // partial att[k,h] = a[k, o-chunk] · awT[h, o-chunk]^T  (own strip)
    f32x4 attacc[4] = {};
    if (act) {
        #pragma unroll
        for (int ds = 0; ds < 2; ++ds) {
            bf16x8 bw = *reinterpret_cast<const bf16x8*>(&awT[l15 * 72 + ds * 32 + lgp * 8]);
            #pragma unroll
            for (int kt = 0; kt < 4; ++kt) {
                int row = w * 64 + kt * 16 + l15;
                int c16 = ((ds * 4 + lgp) ^ (l15 & 7)) * 8;
                bf16x8 af = *reinterpret_cast<const bf16x8*>(&a_lds[row * 64 + c16]);
                attacc[kt] = __builtin_amdgcn_mfma_f32_16x16x32_bf16(af, bw, attacc[kt], 0, 0, 0);
            }
        }
        // direct write: attpart[(b,j,oc)][k][h] for own strip
        float* dst = attpart + ((size_t)blockIdx.x) * 256 * 8;
        #pragma unroll
        for (int kt = 0; kt < 4; ++kt) {
            if (l15 < 8) {
                #pragma unroll
                for (int i = 0; i < 4; ++i) {
                    int k = w * 64 + kt * 16 + lgp * 4 + i;
                    dst[k * 8 + l15] = attacc[kt][i];
                }
            }
        }
        // mirror write: att[k][j] for strips strictly above the diagonal strip
        if (w > jt && l15 < 8) {
            #pragma unroll
            for (int kt = 0; kt < 4; ++kt) {
                #pragma unroll
                for (int i = 0; i < 4; ++i) {
                    int k = w * 64 + kt * 16 + lgp * 4 + i;
                    attpart[(((size_t)(b * 256 + k)) * 4 + oc) * 2048 + j * 8 + l15] = attacc[kt][i];
                }
            }
        }
    }
}

// ---------- K1b: sum 4 oc-parts + mask + softmax -> p_ws ----------
__global__ void k1b_sm(const float* __restrict__ attpart, const int* __restrict__ bnd,
                       u16* __restrict__ p_ws)
{
    const int b = blockIdx.x >> 8;
    const int j = blockIdx.x & 255;
    const int tid = threadIdx.x;

    __shared__ float attL[256 * 9];
    __shared__ float maskv[256];
    __shared__ int scanv[256];

    scanv[tid] = bnd[b * T_ + tid];
    __syncthreads();
    for (int off = 1; off < 256; off <<= 1) {
        int v = (tid >= off) ? scanv[tid - off] : 0;
        __syncthreads();
        scanv[tid] += v;
        __syncthreads();
    }
    {
        int k = tid;
        float m;
        if (k == j) m = 1.f;
        else if (k > j) m = ((scanv[k] - (j ? scanv[j - 1] : 0)) == 0) ? 1.f : 0.f;
        else m = ((scanv[j] - (k ? scanv[k - 1] : 0)) == 0) ? 1.f : 0.f;
        maskv[k] = m;
    }
    {
        const float* base = attpart + ((size_t)(b * 256 + j) * 4) * 256 * 8 + tid * 8;
        f32x4 s0 = *reinterpret_cast<const f32x4*>(base);
        f32x4 s1 = *reinterpret_cast<const f32x4*>(base + 4);
        #pragma unroll
        for (int oc = 1; oc < 4; ++oc) {
            s0 += *reinterpret_cast<const f32x4*>(base + (size_t)oc * 2048);
            s1 += *reinterpret_cast<const f32x4*>(base + (size_t)oc * 2048 + 4);
        }
        #pragma unroll
        for (int e = 0; e < 4; ++e) attL[tid * 9 + e] = s0[e];
        #pragma unroll
        for (int e = 0; e < 4; ++e) attL[tid * 9 + 4 + e] = s1[e];
    }
    __syncthreads();

    {
        int h = tid >> 5, c = tid & 31;
        float lgv[8];
        float mx = -3.4e38f;
        #pragma unroll
        for (int kk = 0; kk < 8; ++kk) {
            int k = c + kk * 32;
            float v = attL[k * 9 + h] * maskv[k];
            lgv[kk] = v;
            mx = fmaxf(mx, v);
        }
        #pragma unroll
        for (int off = 1; off < 32; off <<= 1)
            mx = fmaxf(mx, __shfl_xor(mx, off, 32));
        float sum = 0.f;
        #pragma unroll
        for (int kk = 0; kk < 8; ++kk) {
            lgv[kk] = __expf(lgv[kk] - mx);
            sum += lgv[kk];
        }
        #pragma unroll
        for (int off = 1; off < 32; off <<= 1)
            sum += __shfl_xor(sum, off, 32);
        float inv = 1.f / sum;
        u16* dst = p_ws + (((b * 8 + h) * 256 + j) * 256);
        #pragma unroll
        for (int kk = 0; kk < 8; ++kk)
            dst[c + kk * 32] = f2b(lgv[kk] * inv);
    }
}

// ---------- K2: x1[b][j][d*8+h] = sum_k p[b,h,j,k] * x[b,k,d] (MFMA) ----------
__launch_bounds__(256, 2)
__global__ void k2_agg(const u16* __restrict__ p_ws, const u16* __restrict__ XT,
                       u16* __restrict__ x1)
{
    const int bh = blockIdx.x >> 3;
    const int dc = blockIdx.x & 7;
    const int b = bh >> 3;
    const int h = bh & 7;
    const int tid = threadIdx.x;
    const int w = tid >> 6, l = tid & 63, l15 = l & 15, lgp = l >> 4;

    __shared__ __align__(16) u16 AL[256 * 72];
    __shared__ __align__(16) u16 BL[64 * 72];

    const u16* A = p_ws + bh * (256 * 256);
    const u16* Bx = XT + (b * 512 + dc * 64) * 256;

    f32x4 acc[4][4] = {};
    for (int k0 = 0; k0 < 256; k0 += 64) {
        __syncthreads();
        #pragma unroll
        for (int c = 0; c < 8; ++c) {
            int cc = tid + c * 256;
            int r = cc >> 3, s = cc & 7;
            *reinterpret_cast<uint4*>(&AL[r * 72 + s * 8]) =
                *reinterpret_cast<const uint4*>(A + r * 256 + k0 + s * 8);
        }
        #pragma unroll
        for (int c = 0; c < 2; ++c) {
            int cc = tid + c * 256;
            int r = cc >> 3, s = cc & 7;
            *reinterpret_cast<uint4*>(&BL[r * 72 + s * 8]) =
                *reinterpret_cast<const uint4*>(Bx + r * 256 + k0 + s * 8);
        }
        __syncthreads();
        #pragma unroll
        for (int ds = 0; ds < 2; ++ds) {
            bf16x8 bfr[4];
            #pragma unroll
            for (int ot = 0; ot < 4; ++ot)
                bfr[ot] = *reinterpret_cast<const bf16x8*>(&BL[(ot * 16 + l15) * 72 + ds * 32 + lgp * 8]);
            #pragma unroll
            for (int kt = 0; kt < 4; ++kt) {
                bf16x8 afr = *reinterpret_cast<const bf16x8*>(&AL[(w * 64 + kt * 16 + l15) * 72 + ds * 32 + lgp * 8]);
                #pragma unroll
                for (int ot = 0; ot < 4; ++ot)
                    acc[kt][ot] = __builtin_amdgcn_mfma_f32_16x16x32_bf16(afr, bfr[ot], acc[kt][ot], 0, 0, 0);
            }
        }
    }
    #pragma unroll
    for (int kt = 0; kt < 4; ++kt)
        #pragma unroll
        for (int ot = 0; ot < 4; ++ot)
            #pragma unroll
            for (int i = 0; i < 4; ++i) {
                int jj = w * 64 + kt * 16 + lgp * 4 + i;
                int d = dc * 64 + ot * 16 + l15;
                x1[(b * 256 + jj) * 4096 + d * 8 + h] = f2b(acc[kt][ot][i]);
            }
}

// ---------- K3: split-K projections -> 5 partial buffers ----------
__launch_bounds__(256, 4)
__global__ void k3_mm(const u16* __restrict__ x1, const float* __restrict__ x,
                      const float* __restrict__ W2, const float* __restrict__ W3,
                      float* __restrict__ part)
{
    const int gid = blockIdx.x;
    const int tid = threadIdx.x;
    const int w = tid >> 6, l = tid & 63, l15 = l & 15, lgp = l >> 4;

    __shared__ __align__(16) u16 AL[64 * 72];
    __shared__ __align__(16) u16 BL[64 * 72];

    f32x4 acc[4] = {};
    int jc, oc, slot;
    if (gid < 128) {
        int kc = gid & 3;
        oc = (gid >> 2) & 3;
        jc = gid >> 4;
        slot = kc;
        const int j0 = jc * 64, o0 = oc * 64;
        const int tbeg = kc * 1024, tend = tbeg + 1024;
        for (int t0 = tbeg; t0 < tend; t0 += 64) {
            __syncthreads();
            #pragma unroll
            for (int c = 0; c < 2; ++c) {
                int cc = tid + c * 256;
                int r = cc >> 3, s = cc & 7;
                *reinterpret_cast<uint4*>(&AL[r * 72 + s * 8]) =
                    *reinterpret_cast<const uint4*>(x1 + (size_t)(j0 + r) * 4096 + t0 + s * 8);
                *reinterpret_cast<uint4*>(&BL[r * 72 + s * 8]) =
                    ld8f2b(W2 + (size_t)(o0 + r) * 4096 + t0 + s * 8);
            }
            __syncthreads();
            #pragma unroll
            for (int ds = 0; ds < 2; ++ds) {
                bf16x8 afr = *reinterpret_cast<const bf16x8*>(&AL[(w * 16 + l15) * 72 + ds * 32 + lgp * 8]);
                #pragma unroll
                for (int ot = 0; ot < 4; ++ot) {
                    bf16x8 bfr = *reinterpret_cast<const bf16x8*>(&BL[(ot * 16 + l15) * 72 + ds * 32 + lgp * 8]);
                    acc[ot] = __builtin_amdgcn_mfma_f32_16x16x32_bf16(afr, bfr, acc[ot], 0, 0, 0);
                }
            }
        }
    } else {
        int g2 = gid - 128;
        oc = g2 & 3;
        jc = g2 >> 2;
        slot = 4;
        const int j0 = jc * 64, o0 = oc * 64;
        for (int t0 = 0; t0 < 512; t0 += 64) {
            __syncthreads();
            #pragma unroll
            for (int c = 0; c < 2; ++c) {
                int cc = tid + c * 256;
                int r = cc >> 3, s = cc & 7;
                *reinterpret_cast<uint4*>(&AL[r * 72 + s * 8]) =
                    ld8f2b(x + (size_t)(j0 + r) * 512 + t0 + s * 8);
                *reinterpret_cast<uint4*>(&BL[r * 72 + s * 8]) =
                    ld8f2b(W3 + (size_t)(o0 + r) * 512 + t0 + s * 8);
            }
            __syncthreads();
            #pragma unroll
            for (int ds = 0; ds < 2; ++ds) {
                bf16x8 afr = *reinterpret_cast<const bf16x8*>(&AL[(w * 16 + l15) * 72 + ds * 32 + lgp * 8]);
                #pragma unroll
                for (int ot = 0; ot < 4; ++ot) {
                    bf16x8 bfr = *reinterpret_cast<const bf16x8*>(&BL[(ot * 16 + l15) * 72 + ds * 32 + lgp * 8]);
                    acc[ot] = __builtin_amdgcn_mfma_f32_16x16x32_bf16(afr, bfr, acc[ot], 0, 0, 0);
                }
            }
        }
    }
    const int j0 = jc * 64, o0 = oc * 64;
    float* dst = part + (size_t)slot * 512 * 256;
    #pragma unroll
    for (int ot = 0; ot < 4; ++ot)
        #pragma unroll
        for (int i = 0; i < 4; ++i) {
            int rr = j0 + w * 16 + lgp * 4 + i;
            int o = o0 + ot * 16 + l15;
            dst[rr * 256 + o] = acc[ot][i];
        }
}

// ---------- K4a: combine partials + biases -> ypre, per-chunk BN stats ----------
__global__ void k4a_comb(const float* __restrict__ part,
                         const float* __restrict__ pb2, const float* __restrict__ pb3,
                         float* __restrict__ ypre,
                         float* __restrict__ psum, float* __restrict__ psq)
{
    int g = blockIdx.x, o = threadIdx.x;
    float bsum = pb2[o] + pb3[o];
    float s = 0.f, q = 0.f;
    for (int r = g * 8; r < g * 8 + 8; ++r) {
        size_t idx = (size_t)r * 256 + o;
        float v = part[idx] + part[131072 + idx] + part[2 * 131072 + idx]
                + part[3 * 131072 + idx] + part[4 * 131072 + idx] + bsum;
        ypre[idx] = v;
        s += v; q += v * v;
    }
    psum[g * 256 + o] = s;
    psq[g * 256 + o] = q;
}

// ---------- K4c: fold 64-chunk stats -> mu, inv ----------
__global__ void k4c_stats(const float* __restrict__ psum, const float* __restrict__ psq,
                          float* __restrict__ mu, float* __restrict__ inv) {
    int o = threadIdx.x;
    float s = 0.f, q = 0.f;
    for (int g = 0; g < 64; ++g) {
        s += psum[g * 256 + o];
        q += psq[g * 256 + o];
    }
    float m = s * (1.f / 512.f);
    float var = q * (1.f / 512.f) - m * m;
    mu[o] = m;
    inv[o] = rsqrtf(var + 1e-5f);
}

// ---------- K4b: normalize + affine + SELU -> FP32 output ----------
__global__ void k4b_norm(const float* __restrict__ ypre,
                         const float* __restrict__ mu, const float* __restrict__ inv,
                         const float* __restrict__ gamma, const float* __restrict__ beta,
                         float* __restrict__ out) {
    int r = blockIdx.x, o = threadIdx.x;
    float v = (ypre[r * 256 + o] - mu[o]) * inv[o] * gamma[o] + beta[o];
    const float SC = 1.0507009873554805f, AL = 1.6732632423543772f;
    float ov = v > 0.f ? SC * v : SC * AL * (__expf(v) - 1.f);
    out[r * 256 + o] = ov;
}

extern "C" void kernel_launch(void* const* d_in, const int* in_sizes, int n_in,
                              void* d_out, int out_size, void* d_ws, size_t ws_size,
                              hipStream_t stream) {
    const float* x    = (const float*)d_in[0];
    const int* bnd    = (const int*)d_in[1];
    const float* Wap  = (const float*)d_in[2];
    const float* bap  = (const float*)d_in[3];
    const float* aw   = (const float*)d_in[4];
    const float* W2   = (const float*)d_in[5];
    const float* pb2  = (const float*)d_in[6];
    const float* W3   = (const float*)d_in[7];
    const float* pb3  = (const float*)d_in[8];
    const float* gamma = (const float*)d_in[9];
    const float* beta  = (const float*)d_in[10];
    float* out = (float*)d_out;
    (void)in_sizes; (void)n_in; (void)out_size; (void)ws_size;

    char* ws = (char*)d_ws;
    u16* Xbf   = (u16*)ws;  ws += (size_t)B_ * T_ * D_ * 2;         // 512 KB
    u16* XT    = (u16*)ws;  ws += (size_t)B_ * D_ * T_ * 2;         // 512 KB
    u16* p_ws  = (u16*)ws;  ws += (size_t)B_ * H_ * T_ * T_ * 2;    // 2 MB
    u16* x1    = (u16*)ws;  ws += (size_t)B_ * T_ * D_ * H_ * 2;    // 4 MB
    float* part = (float*)ws; ws += (size_t)5 * 512 * 256 * 4;      // 2.6 MB
    float* ypre = (float*)ws; ws += (size_t)B_ * T_ * O_ * 4;       // 512 KB
    float* psum = (float*)ws; ws += (size_t)64 * O_ * 4;
    float* psq  = (float*)ws; ws += (size_t)64 * O_ * 4;
    float* muv  = (float*)ws; ws += (size_t)O_ * 4;
    float* invv = (float*)ws; ws += (size_t)O_ * 4;
    float* attpart = (float*)ws; ws += (size_t)2048 * 256 * 8 * 4;  // 16.8 MB

    k0_convert<<<64, 256, 0, stream>>>(x, Xbf, XT);
    k1a_att<<<2048, 256, 0, stream>>>(Xbf, x, Wap, bap, aw, attpart);
    k1b_sm<<<512, 256, 0, stream>>>(attpart, bnd, p_ws);
    k2_agg<<<128, 256, 0, stream>>>(p_ws, XT, x1);
    k3_mm<<<160, 256, 0, stream>>>(x1, x, W2, W3, part);
    k4a_comb<<<64, 256, 0, stream>>>(part, pb2, pb3, ypre, psum, psq);
    k4c_stats<<<1, 256, 0, stream>>>(psum, psq, muv, invv);
    k4b_norm<<<512, 256, 0, stream>>>(ypre, muv, invv, gamma, beta, out);
}

// Round 12
// 107.287 us; speedup vs baseline: 14.3275x; 1.0314x over previous
//
#include <hip/hip_runtime.h>
#include <hip/hip_bf16.h>

// Problem: B=2, T=256, IN_DIM=512, OUT_DIM=256, H=8, TEMP=1, BN_EPS=1e-5
// Device dtypes: inputs fp32 (boundary int32), OUTPUT fp32.
// ROUND 12: v_cvt_pk_bf16_f32 packed converts in all hot f32->bf16 paths
// (k1a W-stage, tanh epilogue, k3 staging); k4c folded into k4b.
#define B_ 2
#define T_ 256
#define D_ 512
#define O_ 256
#define H_ 8

typedef __attribute__((ext_vector_type(4))) float f32x4;
typedef __attribute__((ext_vector_type(8))) short bf16x8;
typedef unsigned short u16;
typedef unsigned int u32;

__device__ __forceinline__ float b2f(u16 u) {
    u32 t = ((u32)u) << 16;
    return __builtin_bit_cast(float, t);
}
__device__ __forceinline__ u16 f2b(float f) {
    u32 u = __builtin_bit_cast(u32, f);
    u32 r = (u + 0x7FFFu + ((u >> 16) & 1u)) >> 16;  // RNE
    return (u16)r;
}
// packed f32x2 -> bf16x2 (RNE), single instruction
__device__ __forceinline__ u32 cvtpk(float lo, float hi) {
    u32 r;
    asm("v_cvt_pk_bf16_f32 %0, %1, %2" : "=v"(r) : "v"(lo), "v"(hi));
    return r;
}
__device__ __forceinline__ float fast_tanh(float x) {
    float ax = fabsf(x);
    float e = __expf(-2.f * ax);
    float r = (1.f - e) / (1.f + e);
    return x < 0.f ? -r : r;
}
// load 8 consecutive fp32 -> 8 bf16 packed (cvt_pk path)
__device__ __forceinline__ uint4 ld8f2b(const float* __restrict__ p) {
    f32x4 a = *reinterpret_cast<const f32x4*>(p);
    f32x4 b = *reinterpret_cast<const f32x4*>(p + 4);
    uint4 pk;
    pk.x = cvtpk(a[0], a[1]);
    pk.y = cvtpk(a[2], a[3]);
    pk.z = cvtpk(b[0], b[1]);
    pk.w = cvtpk(b[2], b[3]);
    return pk;
}
__device__ __forceinline__ void gload16(const void* g, void* l) {
    __builtin_amdgcn_global_load_lds(
        (const __attribute__((address_space(1))) unsigned int*)g,
        (__attribute__((address_space(3))) unsigned int*)l, 16, 0, 0);
}

// ---------- K0: Xbf[b][k][d] = bf16(x), XT[b][d][k] = bf16(x[b][k][d]) ----------
__global__ void k0_convert(const float* __restrict__ x,
                           u16* __restrict__ Xbf, u16* __restrict__ XT) {
    int idx = blockIdx.x;
    int dt = idx & 7, kt = (idx >> 3) & 3, b = idx >> 5;
    __shared__ u16 tile[64][65];
    int tid = threadIdx.x;
    for (int c = tid; c < 4096; c += 256) {
        int r = c >> 6, col = c & 63;
        float v = x[(b * 256 + kt * 64 + r) * 512 + dt * 64 + col];
        u16 hv = f2b(v);
        tile[r][col] = hv;
        Xbf[(b * 256 + kt * 64 + r) * 512 + dt * 64 + col] = hv;
    }
    __syncthreads();
    for (int c = tid; c < 4096; c += 256) {
        int rr = c >> 6, cc = c & 63;
        XT[(b * 512 + dt * 64 + rr) * 256 + kt * 64 + cc] = tile[cc][rr];
    }
}

// ---------- K1a: per-(b,j,oc) pair-GEMM + tanh + partial att, symmetric-half ----------
__launch_bounds__(256, 3)
__global__ void k1a_att(const u16* __restrict__ Xbf, const float* __restrict__ xf,
                        const float* __restrict__ Wap, const float* __restrict__ bap,
                        const float* __restrict__ aw, float* __restrict__ attpart)
{
    const int oc = blockIdx.x & 3;
    const int j = (blockIdx.x >> 2) & 255;
    const int b = blockIdx.x >> 10;
    const int jt = j >> 6;
    const int tid = threadIdx.x;
    const int w = tid >> 6;
    const int l = tid & 63;
    const int l15 = l & 15;
    const int lgp = l >> 4;
    const bool act = (w >= jt);

    __shared__ __align__(16) u16 XL[256 * 64];   // swizzled DMA dest; reused as a_lds
    __shared__ __align__(16) u16 WL[64 * 72];    // Wj tile (o_local x 64d), pad 72
    __shared__ __align__(16) u16 awT[16 * 72];   // aw chunk [h][o_local], rows 8..15 zero
    __shared__ float xj[512];

    const u16* xb = Xbf + b * (T_ * D_);
    const float* xjp = xf + (b * T_ + j) * D_;
    for (int i = tid; i < D_; i += 256) xj[i] = xjp[i];
    for (int i = tid; i < 16 * 72; i += 256) awT[i] = 0;
    __syncthreads();
    for (int i = tid; i < 64 * 8; i += 256) {
        int ol = i >> 3, h = i & 7;
        awT[h * 72 + ol] = f2b(aw[(oc * 64 + ol) * 8 + h]);
    }

    const int srow_off = (l >> 3);
    const int scol = ((l & 7) ^ ((l >> 3) & 7)) * 8;
    const int i0 = jt * 2;

    f32x4 acc[4][4] = {};              // C'[o,k] tiles [ot][kt]
    for (int d0 = 0; d0 < D_; d0 += 64) {
        __syncthreads();
        #pragma unroll
        for (int i = 0; i < 8; ++i) {
            if (i >= i0) {
                int row = i * 32 + w * 8 + srow_off;
                gload16(xb + row * 512 + d0 + scol, &XL[i * 2048 + w * 512]);
            }
        }
        #pragma unroll
        for (int c = 0; c < 2; ++c) {
            int cc = tid + c * 256;
            int r = cc >> 3, s = cc & 7;
            const float* wp = Wap + (oc * 64 + r) * 512 + d0 + s * 8;
            f32x4 va = *reinterpret_cast<const f32x4*>(wp);
            f32x4 vb = *reinterpret_cast<const f32x4*>(wp + 4);
            f32x4 xa = *reinterpret_cast<const f32x4*>(&xj[d0 + s * 8]);
            f32x4 xc = *reinterpret_cast<const f32x4*>(&xj[d0 + s * 8 + 4]);
            uint4 pk;
            pk.x = cvtpk(va[0] * xa[0], va[1] * xa[1]);
            pk.y = cvtpk(va[2] * xa[2], va[3] * xa[3]);
            pk.z = cvtpk(vb[0] * xc[0], vb[1] * xc[1]);
            pk.w = cvtpk(vb[2] * xc[2], vb[3] * xc[3]);
            *reinterpret_cast<uint4*>(&WL[r * 72 + s * 8]) = pk;
        }
        __syncthreads();
        if (act) {
            #pragma unroll
            for (int ds = 0; ds < 2; ++ds) {
                bf16x8 wfr[4];
                #pragma unroll
                for (int ot = 0; ot < 4; ++ot)
                    wfr[ot] = *reinterpret_cast<const bf16x8*>(&WL[(ot * 16 + l15) * 72 + ds * 32 + lgp * 8]);
                #pragma unroll
                for (int kt = 0; kt < 4; ++kt) {
                    int row = w * 64 + kt * 16 + l15;
                    int c16 = ((ds * 4 + lgp) ^ (l15 & 7)) * 8;
                    bf16x8 xfr = *reinterpret_cast<const bf16x8*>(&XL[row * 64 + c16]);
                    #pragma unroll
                    for (int ot = 0; ot < 4; ++ot)
                        acc[ot][kt] = __builtin_amdgcn_mfma_f32_16x16x32_bf16(wfr[ot], xfr, acc[ot][kt], 0, 0, 0);
                }
            }
        }
    }
    u16* a_lds = XL;
    if (act) {
        #pragma unroll
        for (int ot = 0; ot < 4; ++ot) {
            f32x4 bv = *reinterpret_cast<const f32x4*>(bap + oc * 64 + ot * 16 + lgp * 4);
            #pragma unroll
            for (int kt = 0; kt < 4; ++kt) {
                int k = w * 64 + kt * 16 + l15;
                float t0 = fast_tanh(acc[ot][kt][0] + bv[0]);
                float t1 = fast_tanh(acc[ot][kt][1] + bv[1]);
                float t2 = fast_tanh(acc[ot][kt][2] + bv[2]);
                float t3 = fast_tanh(acc[ot][kt][3] + bv[3]);
                uint2 pk;
                pk.x = cvtpk(t0, t1);
                pk.y = cvtpk(t2, t3);
                int c16 = (ot * 2 + (lgp >> 1)) ^ (l15 & 7);
                *reinterpret_cast<uint2*>(&a_lds[k * 64 + c16 * 8 + (lgp & 1) * 4]) = pk;
            }
        }
    }
    f32x4 attacc[4] = {};
    if (act) {
        #pragma unroll
        for (int ds = 0; ds < 2; ++ds) {
            bf16x8 bw = *reinterpret_cast<const bf16x8*>(&awT[l15 * 72 + ds * 32 + lgp * 8]);
            #pragma unroll
            for (int kt = 0; kt < 4; ++kt) {
                int row = w * 64 + kt * 16 + l15;
                int c16 = ((ds * 4 + lgp) ^ (l15 & 7)) * 8;
                bf16x8 af = *reinterpret_cast<const bf16x8*>(&a_lds[row * 64 + c16]);
                attacc[kt] = __builtin_amdgcn_mfma_f32_16x16x32_bf16(af, bw, attacc[kt], 0, 0, 0);
            }
        }
        float* dst = attpart + ((size_t)blockIdx.x) * 256 * 8;
        #pragma unroll
        for (int kt = 0; kt < 4; ++kt) {
            if (l15 < 8) {
                #pragma unroll
                for (int i = 0; i < 4; ++i) {
                    int k = w * 64 + kt * 16 + lgp * 4 + i;
                    dst[k * 8 + l15] = attacc[kt][i];
                }
            }
        }
        if (w > jt && l15 < 8) {
            #pragma unroll
            for (int kt = 0; kt < 4; ++kt) {
                #pragma unroll
                for (int i = 0; i < 4; ++i) {
                    int k = w * 64 + kt * 16 + lgp * 4 + i;
                    attpart[(((size_t)(b * 256 + k)) * 4 + oc) * 2048 + j * 8 + l15] = attacc[kt][i];
                }
            }
        }
    }
}

// ---------- K1b: sum 4 oc-parts + mask + softmax -> p_ws ----------
__global__ void k1b_sm(const float* __restrict__ attpart, const int* __restrict__ bnd,
                       u16* __restrict__ p_ws)
{
    const int b = blockIdx.x >> 8;
    const int j = blockIdx.x & 255;
    const int tid = threadIdx.x;

    __shared__ float attL[256 * 9];
    __shared__ float maskv[256];
    __shared__ int scanv[256];

    scanv[tid] = bnd[b * T_ + tid];
    __syncthreads();
    for (int off = 1; off < 256; off <<= 1) {
        int v = (tid >= off) ? scanv[tid - off] : 0;
        __syncthreads();
        scanv[tid] += v;
        __syncthreads();
    }
    {
        int k = tid;
        float m;
        if (k == j) m = 1.f;
        else if (k > j) m = ((scanv[k] - (j ? scanv[j - 1] : 0)) == 0) ? 1.f : 0.f;
        else m = ((scanv[j] - (k ? scanv[k - 1] : 0)) == 0) ? 1.f : 0.f;
        maskv[k] = m;
    }
    {
        const float* base = attpart + ((size_t)(b * 256 + j) * 4) * 256 * 8 + tid * 8;
        f32x4 s0 = *reinterpret_cast<const f32x4*>(base);
        f32x4 s1 = *reinterpret_cast<const f32x4*>(base + 4);
        #pragma unroll
        for (int oc = 1; oc < 4; ++oc) {
            s0 += *reinterpret_cast<const f32x4*>(base + (size_t)oc * 2048);
            s1 += *reinterpret_cast<const f32x4*>(base + (size_t)oc * 2048 + 4);
        }
        #pragma unroll
        for (int e = 0; e < 4; ++e) attL[tid * 9 + e] = s0[e];
        #pragma unroll
        for (int e = 0; e < 4; ++e) attL[tid * 9 + 4 + e] = s1[e];
    }
    __syncthreads();

    {
        int h = tid >> 5, c = tid & 31;
        float lgv[8];
        float mx = -3.4e38f;
        #pragma unroll
        for (int kk = 0; kk < 8; ++kk) {
            int k = c + kk * 32;
            float v = attL[k * 9 + h] * maskv[k];
            lgv[kk] = v;
            mx = fmaxf(mx, v);
        }
        #pragma unroll
        for (int off = 1; off < 32; off <<= 1)
            mx = fmaxf(mx, __shfl_xor(mx, off, 32));
        float sum = 0.f;
        #pragma unroll
        for (int kk = 0; kk < 8; ++kk) {
            lgv[kk] = __expf(lgv[kk] - mx);
            sum += lgv[kk];
        }
        #pragma unroll
        for (int off = 1; off < 32; off <<= 1)
            sum += __shfl_xor(sum, off, 32);
        float inv = 1.f / sum;
        u16* dst = p_ws + (((b * 8 + h) * 256 + j) * 256);
        #pragma unroll
        for (int kk = 0; kk < 8; ++kk)
            dst[c + kk * 32] = f2b(lgv[kk] * inv);
    }
}

// ---------- K2: x1[b][j][d*8+h] = sum_k p[b,h,j,k] * x[b,k,d] (MFMA) ----------
__launch_bounds__(256, 2)
__global__ void k2_agg(const u16* __restrict__ p_ws, const u16* __restrict__ XT,
                       u16* __restrict__ x1)
{
    const int bh = blockIdx.x >> 3;
    const int dc = blockIdx.x & 7;
    const int b = bh >> 3;
    const int h = bh & 7;
    const int tid = threadIdx.x;
    const int w = tid >> 6, l = tid & 63, l15 = l & 15, lgp = l >> 4;

    __shared__ __align__(16) u16 AL[256 * 72];
    __shared__ __align__(16) u16 BL[64 * 72];

    const u16* A = p_ws + bh * (256 * 256);
    const u16* Bx = XT + (b * 512 + dc * 64) * 256;

    f32x4 acc[4][4] = {};
    for (int k0 = 0; k0 < 256; k0 += 64) {
        __syncthreads();
        #pragma unroll
        for (int c = 0; c < 8; ++c) {
            int cc = tid + c * 256;
            int r = cc >> 3, s = cc & 7;
            *reinterpret_cast<uint4*>(&AL[r * 72 + s * 8]) =
                *reinterpret_cast<const uint4*>(A + r * 256 + k0 + s * 8);
        }
        #pragma unroll
        for (int c = 0; c < 2; ++c) {
            int cc = tid + c * 256;
            int r = cc >> 3, s = cc & 7;
            *reinterpret_cast<uint4*>(&BL[r * 72 + s * 8]) =
                *reinterpret_cast<const uint4*>(Bx + r * 256 + k0 + s * 8);
        }
        __syncthreads();
        #pragma unroll
        for (int ds = 0; ds < 2; ++ds) {
            bf16x8 bfr[4];
            #pragma unroll
            for (int ot = 0; ot < 4; ++ot)
                bfr[ot] = *reinterpret_cast<const bf16x8*>(&BL[(ot * 16 + l15) * 72 + ds * 32 + lgp * 8]);
            #pragma unroll
            for (int kt = 0; kt < 4; ++kt) {
                bf16x8 afr = *reinterpret_cast<const bf16x8*>(&AL[(w * 64 + kt * 16 + l15) * 72 + ds * 32 + lgp * 8]);
                #pragma unroll
                for (int ot = 0; ot < 4; ++ot)
                    acc[kt][ot] = __builtin_amdgcn_mfma_f32_16x16x32_bf16(afr, bfr[ot], acc[kt][ot], 0, 0, 0);
            }
        }
    }
    #pragma unroll
    for (int kt = 0; kt < 4; ++kt)
        #pragma unroll
        for (int ot = 0; ot < 4; ++ot)
            #pragma unroll
            for (int i = 0; i < 4; ++i) {
                int jj = w * 64 + kt * 16 + lgp * 4 + i;
                int d = dc * 64 + ot * 16 + l15;
                x1[(b * 256 + jj) * 4096 + d * 8 + h] = f2b(acc[kt][ot][i]);
            }
}

// ---------- K3: split-K projections -> 5 partial buffers ----------
__launch_bounds__(256, 4)
__global__ void k3_mm(const u16* __restrict__ x1, const float* __restrict__ x,
                      const float* __restrict__ W2, const float* __restrict__ W3,
                      float* __restrict__ part)
{
    const int gid = blockIdx.x;
    const int tid = threadIdx.x;
    const int w = tid >> 6, l = tid & 63, l15 = l & 15, lgp = l >> 4;

    __shared__ __align__(16) u16 AL[64 * 72];
    __shared__ __align__(16) u16 BL[64 * 72];

    f32x4 acc[4] = {};
    int jc, oc, slot;
    if (gid < 128) {
        int kc = gid & 3;
        oc = (gid >> 2) & 3;
        jc = gid >> 4;
        slot = kc;
        const int j0 = jc * 64, o0 = oc * 64;
        const int tbeg = kc * 1024, tend = tbeg + 1024;
        for (int t0 = tbeg; t0 < tend; t0 += 64) {
            __syncthreads();
            #pragma unroll
            for (int c = 0; c < 2; ++c) {
                int cc = tid + c * 256;
                int r = cc >> 3, s = cc & 7;
                *reinterpret_cast<uint4*>(&AL[r * 72 + s * 8]) =
                    *reinterpret_cast<const uint4*>(x1 + (size_t)(j0 + r) * 4096 + t0 + s * 8);
                *reinterpret_cast<uint4*>(&BL[r * 72 + s * 8]) =
                    ld8f2b(W2 + (size_t)(o0 + r) * 4096 + t0 + s * 8);
            }
            __syncthreads();
            #pragma unroll
            for (int ds = 0; ds < 2; ++ds) {
                bf16x8 afr = *reinterpret_cast<const bf16x8*>(&AL[(w * 16 + l15) * 72 + ds * 32 + lgp * 8]);
                #pragma unroll
                for (int ot = 0; ot < 4; ++ot) {
                    bf16x8 bfr = *reinterpret_cast<const bf16x8*>(&BL[(ot * 16 + l15) * 72 + ds * 32 + lgp * 8]);
                    acc[ot] = __builtin_amdgcn_mfma_f32_16x16x32_bf16(afr, bfr, acc[ot], 0, 0, 0);
                }
            }
        }
    } else {
        int g2 = gid - 128;
        oc = g2 & 3;
        jc = g2 >> 2;
        slot = 4;
        const int j0 = jc * 64, o0 = oc * 64;
        for (int t0 = 0; t0 < 512; t0 += 64) {
            __syncthreads();
            #pragma unroll
            for (int c = 0; c < 2; ++c) {
                int cc = tid + c * 256;
                int r = cc >> 3, s = cc & 7;
                *reinterpret_cast<uint4*>(&AL[r * 72 + s * 8]) =
                    ld8f2b(x + (size_t)(j0 + r) * 512 + t0 + s * 8);
                *reinterpret_cast<uint4*>(&BL[r * 72 + s * 8]) =
                    ld8f2b(W3 + (size_t)(o0 + r) * 512 + t0 + s * 8);
            }
            __syncthreads();
            #pragma unroll
            for (int ds = 0; ds < 2; ++ds) {
                bf16x8 afr = *reinterpret_cast<const bf16x8*>(&AL[(w * 16 + l15) * 72 + ds * 32 + lgp * 8]);
                #pragma unroll
                for (int ot = 0; ot < 4; ++ot) {
                    bf16x8 bfr = *reinterpret_cast<const bf16x8*>(&BL[(ot * 16 + l15) * 72 + ds * 32 + lgp * 8]);
                    acc[ot] = __builtin_amdgcn_mfma_f32_16x16x32_bf16(afr, bfr, acc[ot], 0, 0, 0);
                }
            }
        }
    }
    const int j0 = jc * 64, o0 = oc * 64;
    float* dst = part + (size_t)slot * 512 * 256;
    #pragma unroll
    for (int ot = 0; ot < 4; ++ot)
        #pragma unroll
        for (int i = 0; i < 4; ++i) {
            int rr = j0 + w * 16 + lgp * 4 + i;
            int o = o0 + ot * 16 + l15;
            dst[rr * 256 + o] = acc[ot][i];
        }
}

// ---------- K4a: combine partials + biases -> ypre, per-chunk BN stats ----------
__global__ void k4a_comb(const float* __restrict__ part,
                         const float* __restrict__ pb2, const float* __restrict__ pb3,
                         float* __restrict__ ypre,
                         float* __restrict__ psum, float* __restrict__ psq)
{
    int g = blockIdx.x, o = threadIdx.x;
    float bsum = pb2[o] + pb3[o];
    float s = 0.f, q = 0.f;
    for (int r = g * 8; r < g * 8 + 8; ++r) {
        size_t idx = (size_t)r * 256 + o;
        float v = part[idx] + part[131072 + idx] + part[2 * 131072 + idx]
                + part[3 * 131072 + idx] + part[4 * 131072 + idx] + bsum;
        ypre[idx] = v;
        s += v; q += v * v;
    }
    psum[g * 256 + o] = s;
    psq[g * 256 + o] = q;
}

// ---------- K4b: fold stats + normalize + affine + SELU -> FP32 output ----------
__global__ void k4b_norm(const float* __restrict__ ypre,
                         const float* __restrict__ psum, const float* __restrict__ psq,
                         const float* __restrict__ gamma, const float* __restrict__ beta,
                         float* __restrict__ out) {
    int r = blockIdx.x, o = threadIdx.x;
    float s = 0.f, q = 0.f;
    #pragma unroll 8
    for (int g = 0; g < 64; ++g) {
        s += psum[g * 256 + o];
        q += psq[g * 256 + o];
    }
    float mu = s * (1.f / 512.f);
    float var = q * (1.f / 512.f) - mu * mu;
    float inv = rsqrtf(var + 1e-5f);
    float v = (ypre[r * 256 + o] - mu) * inv * gamma[o] + beta[o];
    const float SC = 1.0507009873554805f, AL = 1.6732632423543772f;
    float ov = v > 0.f ? SC * v : SC * AL * (__expf(v) - 1.f);
    out[r * 256 + o] = ov;
}

extern "C" void kernel_launch(void* const* d_in, const int* in_sizes, int n_in,
                              void* d_out, int out_size, void* d_ws, size_t ws_size,
                              hipStream_t stream) {
    const float* x    = (const float*)d_in[0];
    const int* bnd    = (const int*)d_in[1];
    const float* Wap  = (const float*)d_in[2];
    const float* bap  = (const float*)d_in[3];
    const float* aw   = (const float*)d_in[4];
    const float* W2   = (const float*)d_in[5];
    const float* pb2  = (const float*)d_in[6];
    const float* W3   = (const float*)d_in[7];
    const float* pb3  = (const float*)d_in[8];
    const float* gamma = (const float*)d_in[9];
    const float* beta  = (const float*)d_in[10];
    float* out = (float*)d_out;
    (void)in_sizes; (void)n_in; (void)out_size; (void)ws_size;

    char* ws = (char*)d_ws;
    u16* Xbf   = (u16*)ws;  ws += (size_t)B_ * T_ * D_ * 2;
    u16* XT    = (u16*)ws;  ws += (size_t)B_ * D_ * T_ * 2;
    u16* p_ws  = (u16*)ws;  ws += (size_t)B_ * H_ * T_ * T_ * 2;
    u16* x1    = (u16*)ws;  ws += (size_t)B_ * T_ * D_ * H_ * 2;
    float* part = (float*)ws; ws += (size_t)5 * 512 * 256 * 4;
    float* ypre = (float*)ws; ws += (size_t)B_ * T_ * O_ * 4;
    float* psum = (float*)ws; ws += (size_t)64 * O_ * 4;
    float* psq  = (float*)ws; ws += (size_t)64 * O_ * 4;
    float* attpart = (float*)ws; ws += (size_t)2048 * 256 * 8 * 4;

    k0_convert<<<64, 256, 0, stream>>>(x, Xbf, XT);
    k1a_att<<<2048, 256, 0, stream>>>(Xbf, x, Wap, bap, aw, attpart);
    k1b_sm<<<512, 256, 0, stream>>>(attpart, bnd, p_ws);
    k2_agg<<<128, 256, 0, stream>>>(p_ws, XT, x1);
    k3_mm<<<160, 256, 0, stream>>>(x1, x, W2, W3, part);
    k4a_comb<<<64, 256, 0, stream>>>(part, pb2, pb3, ypre, psum, psq);
    k4b_norm<<<512, 256, 0, stream>>>(ypre, psum, psq, gamma, beta, out);
}